// Round 1
// 214.080 us; speedup vs baseline: 1.1189x; 1.1189x over previous
//
#include <hip/hip_runtime.h>
#include <stdint.h>

#define NB 8
#define LL 128
#define NS 1928      // number of spans (l,r), r-l+1 <= 16
#define NK 10        // top-k
#define WPB 4        // waves per block
#define SPW 2        // spans per wave

// span id for (l, r): offset(l) + (r-l)
__device__ __forceinline__ int span_id(int l, int r) {
    int off = (l <= 112) ? (l << 4) : (NS - (((128 - l) * (129 - l)) >> 1));
    return off + (r - l);
}

// Replica of numpy's SIMD float32 exp (verified exact vs oracle in R9/R10).
__device__ __forceinline__ float npexp_f32(float x) {
    const float magic = 12582912.0f;
    const float log2e = 1.442695040888963f;
    const float c1 = -6.93145752e-1f;
    const float c2 = -1.42860677e-6f;
    float t = __fmul_rn(x, log2e);
    float q = __fsub_rn(__fadd_rn(t, magic), magic);
    float r = __fmaf_rn(q, c1, x);
    r = __fmaf_rn(q, c2, r);
    float num = __fmaf_rn(r, 5.082762527590693718096e-04f, 6.757896990527504603057e-03f);
    num = __fmaf_rn(num, r, 5.114512081637298353406e-02f);
    num = __fmaf_rn(num, r, 2.473615434895520810817e-01f);
    num = __fmaf_rn(num, r, 7.257664613233124478488e-01f);
    num = __fmaf_rn(num, r, 9.999999999980870924916e-01f);
    float den = __fmaf_rn(r, 2.159509375685829852307e-02f, -2.742335390411667452936e-01f);
    den = __fmaf_rn(den, r, 1.0f);
    float p = __fdiv_rn(num, den);
    int qi = (int)q;
    return __fmul_rn(p, __int_as_float((127 + qi) << 23));
}

__device__ __forceinline__ float keyval(unsigned long long k) {
    return __uint_as_float((unsigned)(k >> 32));
}

__device__ __forceinline__ void wfence() {
    __builtin_amdgcn_wave_barrier();
    __threadfence_block();
    __builtin_amdgcn_wave_barrier();
}

// Wave-parallel numpy-aquicksort partition (R10-verified semantics), fast form.
__device__ int wave_partition_fast(unsigned long long* a, int* posL, int* posR,
                                   int pl, int pr, int lane) {
    int pm = pl + ((pr - pl) >> 1);
    unsigned long long vl = a[pl], vm = a[pm], vr = a[pr], tt;
    if (keyval(vm) < keyval(vl)) { tt = vm; vm = vl; vl = tt; }
    if (keyval(vr) < keyval(vm)) { tt = vr; vr = vm; vm = tt; }
    if (keyval(vm) < keyval(vl)) { tt = vm; vm = vl; vl = tt; }
    float vp = keyval(vm);
    unsigned long long vq = a[pr - 1];
    if (lane == 0) { a[pl] = vl; a[pr] = vr; a[pm] = vq; a[pr - 1] = vm; }
    wfence();

    unsigned long long lmask = (1ull << lane) - 1ull;
    int baseL = 0, baseR = 0;
    for (int p0 = pl; p0 <= pr; p0 += 64) {
        int pos = p0 + lane;
        bool inr = (pos <= pr);
        float v = inr ? keyval(a[pos]) : 0.0f;
        bool ge = inr && (pos > pl) && (pos < pr) && (v >= vp);
        bool le = inr && (pos <= pr - 2) && (v <= vp);
        unsigned long long bge = __ballot(ge);
        unsigned long long ble = __ballot(le);
        if (ge) posL[baseL + __popcll(bge & lmask)] = pos;
        if (le) posR[baseR + __popcll(ble & lmask)] = pos;
        baseL += __popcll(bge);
        baseR += __popcll(ble);
    }
    wfence();
    int totGE = baseL, totLE = baseR;
    int maxk = (totGE < totLE) ? totGE : totLE;
    int K = 0;
    for (int base = 0;; base += 64) {
        int k = base + lane;
        bool active = (k < maxk);
        int Lk = active ? posL[k] : 0x7fffffff;
        int Rk = active ? posR[totLE - 1 - k] : -1;
        bool sw = active && (Lk < Rk);
        unsigned long long bm = __ballot(sw);     // monotone prefix of true
        int nsw = (~bm == 0ull) ? 64 : (__ffsll((long long)~bm) - 1);
        if (sw && (lane < nsw)) {
            unsigned long long tl = a[Lk], tr = a[Rk];
            a[Lk] = tr; a[Rk] = tl;              // all swapped positions distinct (proof R10)
        }
        K += nsw;
        if (nsw < 64) break;
    }
    wfence();
    int pi = posL[K];                             // K < totGE (pivot at pr-1 never swapped)
    if (K > 0) { int rp = posR[totLE - K]; if (rp < pi) pi = rp; }
    if (lane == 0) { tt = a[pi]; a[pi] = a[pr - 1]; a[pr - 1] = tt; }
    wfence();
    return pi;
}

__device__ __forceinline__ void lane_sift(unsigned long long* h, int start, int hm) {
    unsigned long long tmp = h[start];
    int i = start, j = start + start;
    while (j <= hm) {
        if (j < hm && keyval(h[j]) < keyval(h[j + 1])) ++j;
        if (keyval(tmp) < keyval(h[j])) { h[i] = h[j]; i = j; j += j; }
        else break;
    }
    h[i] = tmp;
}

// numpy aheapsort on a[lo..hi], extracting only positions >= needlo.
__device__ void wave_heap_top(unsigned long long* a, int lo, int hi, int needlo, int lane) {
    unsigned long long* h = a + lo - 1;
    int hm = hi - lo + 1;
    int half = hm >> 1;
    int maxlvl = 0; { int v = half; while (v >>= 1) ++maxlvl; }
    for (int lvl = maxlvl; lvl >= 0; --lvl) {
        int n0 = 1 << lvl;
        int n1 = (n0 << 1) - 1; if (n1 > half) n1 = half;
        for (int nb = n0; nb <= n1; nb += 64) {
            int node = nb + lane;
            if (node <= n1) lane_sift(h, node, hm);
        }
        wfence();
    }
    int E = hi - needlo + 1;
    if (E > hm - 1) E = hm - 1;
    if (lane == 0) {
        int m = hm;
        for (int e = 0; e < E; ++e) {
            unsigned long long tmp = h[m]; h[m] = h[1]; --m;
            int i = 1, j = 2;
            while (j <= m) {
                if (j < m && keyval(h[j]) < keyval(h[j + 1])) ++j;
                if (keyval(tmp) < keyval(h[j])) { h[i] = h[j]; i = j; j += j; }
                else break;
            }
            h[i] = tmp;
        }
    }
    wfence();
}

// stable insertion-sort outcome via parallel stable rank (len <= 16)
__device__ void wave_insertion(unsigned long long* a, int lo, int hi, int lane) {
    int len = hi - lo + 1;
    unsigned long long v = (lane < len) ? a[lo + lane] : 0ull;
    float fv = keyval(v);
    int rank = 0;
    for (int j = 0; j < len; ++j) {
        unsigned long long vj = __shfl(v, j, 64);
        float fj = keyval(vj);
        if ((fj < fv) || (fj == fv && j < lane)) ++rank;
    }
    wfence();
    if (lane < len) a[lo + rank] = v;
    wfence();
}

// numpy introsort (verified semantics: GLOBAL depth budget, SMALL=15,
// push-larger/continue-smaller), computing only positions >= n-NK exactly.
__device__ void wave_np_sort_top(unsigned long long* a, int n, int lane, int* stk,
                                 int* posL, int* posR) {
    int depth = 0; { int v = n; while (v >>= 1) ++depth; }
    depth *= 2;
    const int TOPLO = n - NK;
    int sp = 0;
    int lo = 0, hi = n - 1;
    for (;;) {
        while (hi - lo > 15) {
            if (depth-- < 0) {
                if (hi >= TOPLO) wave_heap_top(a, lo, hi, (lo > TOPLO ? lo : TOPLO), lane);
                goto pop;
            }
            {
                int pi = wave_partition_fast(a, posL, posR, lo, hi, lane);
                if (pi - lo < hi - pi) {
                    if (lane == 0) { stk[sp * 2] = pi + 1; stk[sp * 2 + 1] = hi; }
                    ++sp; hi = pi - 1;
                } else {
                    if (lane == 0) { stk[sp * 2] = lo; stk[sp * 2 + 1] = pi - 1; }
                    ++sp; lo = pi + 1;
                }
                wfence();
            }
        }
        if (hi > lo && hi >= TOPLO) wave_insertion(a, lo, hi, lane);
pop:
        if (sp == 0) break;
        --sp;
        lo = stk[sp * 2]; hi = stk[sp * 2 + 1];
    }
}

// Kernel 1: build packed tables ONCE per batch (was re-done in every scan block),
// fused with top1 extraction.
__global__ __launch_bounds__(256)
void build_tables_kernel(const int* __restrict__ hi, const float* __restrict__ hw,
                         float4* __restrict__ g_pack, uint16_t* __restrict__ g_lrc,
                         unsigned char* __restrict__ top1) {
    int j = blockIdx.x * 256 + threadIdx.x;
    if (j >= NB * LL * 16) return;
    int b = j >> 11;                 // LL*16 = 2048
    int lw = j & 2047;
    int l = lw >> 4, w = lw & 15, r = l + w;
    if (r >= LL) return;
    int sid = span_id(l, r);
    const int* hb = hi + b * LL * LL * 4;
    const float* wb = hw + b * LL * LL * 4;
    int4 iv = *(const int4*)(hb + (l * LL + r) * 4);
    float4 wv = *(const float4*)(wb + (l * LL + r) * 4);
    int ia = iv.x, ib = iv.y, ic = iv.z;
    float wa = wv.x, wb2 = wv.y, wc = wv.z;
    int m0, m1 = 255, m2 = 255;
    float W0, W1 = 0.f, W2 = 0.f;
    if (ia == ib && ib == ic) {
        m0 = ia; W0 = __fadd_rn(__fadd_rn(wa, wb2), wc);
    } else if (ia == ib) {
        float W = __fadd_rn(wa, wb2);
        if (ia < ic) { m0 = ia; W0 = W; m1 = ic; W1 = wc; }
        else         { m0 = ic; W0 = wc; m1 = ia; W1 = W; }
    } else if (ia == ic) {
        float W = __fadd_rn(wa, wc);
        if (ia < ib) { m0 = ia; W0 = W; m1 = ib; W1 = wb2; }
        else         { m0 = ib; W0 = wb2; m1 = ia; W1 = W; }
    } else if (ib == ic) {
        float W = __fadd_rn(wb2, wc);
        if (ia < ib) { m0 = ia; W0 = wa; m1 = ib; W1 = W; }
        else         { m0 = ib; W0 = W; m1 = ia; W1 = wa; }
    } else {
        int x0 = ia, x1 = ib, x2 = ic; float y0 = wa, y1 = wb2, y2 = wc;
        if (x0 > x1) { int tx = x0; x0 = x1; x1 = tx; float ty = y0; y0 = y1; y1 = ty; }
        if (x1 > x2) { int tx = x1; x1 = x2; x2 = tx; float ty = y1; y1 = y2; y2 = ty; }
        if (x0 > x1) { int tx = x0; x0 = x1; x1 = tx; float ty = y0; y0 = y1; y1 = ty; }
        m0 = x0; m1 = x1; m2 = x2; W0 = y0; W1 = y1; W2 = y2;
    }
    uint32_t rec = (uint32_t)m0 | ((uint32_t)m1 << 8) | ((uint32_t)m2 << 16)
                 | ((uint32_t)(ia & 127) << 24);
    g_pack[b * NS + sid] = make_float4(W0, W1, W2, __uint_as_float(rec));
    g_lrc[b * NS + sid] = (uint16_t)(l | (r << 7));
    top1[b * NS + sid] = (unsigned char)(ia & 127);
}

// Kernel 2: one wave per (b,l) — cumsum cap (every t written exactly once since
// top1[t] in [0,128)).
__global__ void cap_kernel(const unsigned char* __restrict__ top1,
                           unsigned char* __restrict__ flags) {
    int gw = (blockIdx.x * blockDim.x + threadIdx.x) >> 6;
    int lane = threadIdx.x & 63;
    int b = gw >> 7, l = gw & 127;
    const unsigned char* tb = top1 + b * NS;
    unsigned char* fb = flags + b * NS;
    int cnt = 0;
    for (int t0 = 0; t0 < NS; t0 += 64) {
        int t = t0 + lane;
        int tp = (t < NS) ? (int)tb[t] : 255;
        bool match = (tp == l);
        unsigned long long m = __ballot(match);
        if (match) {
            int pre = __popcll(m & ((1ull << lane) - 1ull));
            fb[t] = (cnt + pre + 1 <= 128) ? 1 : 0;
        }
        cnt += __popcll(m);
    }
}

// Cheap global->LDS table staging (replaces per-block recompute), OR-ing cap bit.
__device__ __forceinline__ void load_tables(const float4* __restrict__ gp,
                                            const uint16_t* __restrict__ gl,
                                            const unsigned char* __restrict__ fb,
                                            float4* s_pack, uint16_t* s_lrc) {
    for (int j = threadIdx.x; j < NS; j += 256) {
        s_pack[j] = gp[j];
        s_lrc[j] = (uint16_t)(gl[j] | ((fb[j] & 1) << 14));
    }
}

// Per-span prologue: q row (wave-wide, 128 entries) + coverage ballots.
__device__ __forceinline__ void span_prologue(const float* __restrict__ db, float4 ps,
                                              int lane, float* qrow,
                                              unsigned long long* ub) {
    uint32_t rec = __float_as_uint(ps.w);
    int m0 = rec & 255, m1 = (rec >> 8) & 255, m2 = (rec >> 16) & 255;
    bool e1 = (m1 != 255), e2 = (m2 != 255);
    const float* row0 = db + m0 * LL;
    const float* row1 = db + (e1 ? m1 : 0) * LL;
    const float* row2 = db + (e2 ? m2 : 0) * LL;
    int mA = lane, mB = lane + 64;
    float dA0 = row0[mA], dB0 = row0[mB];
    float dA1 = row1[mA], dB1 = row1[mB];
    float dA2 = row2[mA], dB2 = row2[mB];
    float qA = __fmaf_rn(ps.x, npexp_f32(-dA0), 0.0f);
    qA = __fmaf_rn(ps.y, npexp_f32(-dA1), qA);
    qA = __fmaf_rn(ps.z, npexp_f32(-dA2), qA);
    float qB = __fmaf_rn(ps.x, npexp_f32(-dB0), 0.0f);
    qB = __fmaf_rn(ps.y, npexp_f32(-dB1), qB);
    qB = __fmaf_rn(ps.z, npexp_f32(-dB2), qB);
    bool cA = (dA0 <= 2.0f || mA == m0) ||
              (e1 && (dA1 <= 2.0f || mA == m1)) ||
              (e2 && (dA2 <= 2.0f || mA == m2));
    bool cB = (dB0 <= 2.0f || mB == m0) ||
              (e1 && (dB1 <= 2.0f || mB == m1)) ||
              (e2 && (dB2 <= 2.0f || mB == m2));
    ub[0] = __ballot(cA);
    ub[1] = __ballot(cB);
    qrow[mA] = qA;
    qrow[mB] = qB;
}

// Sorted top-11 merge step (bit-identical semantics to R10-verified version).
__device__ __forceinline__ void topk_merge(unsigned key, int t0, int lane,
                                           unsigned& v, int& vi, unsigned& tau) {
    unsigned long long bm = __ballot(key > tau);
    while (bm) {
        int ln = __ffsll((long long)bm) - 1;
        bm &= bm - 1;
        unsigned kk = __shfl(key, ln, 64);
        if (kk > tau) {                    // wave-uniform
            int tk = t0 + ln;
            unsigned vprev = __shfl_up(v, 1, 64);
            int iprev = __shfl_up(vi, 1, 64);
            if (lane == 0) vprev = 0xFFFFFFFFu;
            bool keep = (v >= kk);         // equals keep -> new after (asc-t among ties)
            bool fp = (vprev < kk);
            v = keep ? v : (fp ? vprev : kk);
            vi = keep ? vi : (fp ? iprev : tk);
            tau = __shfl(v, 10, 64);
        }
    }
}

__device__ __forceinline__ void span_epilogue(unsigned v, int vi, int b, int s, int lane,
                                              unsigned char* __restrict__ rowflag,
                                              int* __restrict__ out) {
    unsigned vn = __shfl_down(v, 1, 64);
    bool tie = (lane < NK) && (v != 0u) && (vn == v);
    bool flag = (__ballot(tie) != 0ull);
    if (lane < NK) {
        int o = (b * NS + s) * NK + lane;
        out[NB * NS * NK + o] = 1;             // N_mask = ones always
        if (!flag) out[o] = (vi >= 0) ? vi : s;
    }
    if (lane == 0) rowflag[b * NS + s] = flag ? 1 : 0;
}

// Kernel A: fast path — 2 spans per wave, shared candidate decode.
__global__ __launch_bounds__(256)
void span_scan_kernel(const float4* __restrict__ g_pack,
                      const uint16_t* __restrict__ g_lrc,
                      const float* __restrict__ dist,
                      const unsigned char* __restrict__ capf,
                      unsigned char* __restrict__ rowflag,
                      int* __restrict__ out) {
    __shared__ float4 s_pack[NS];
    __shared__ uint16_t s_lrc[NS];
    __shared__ float s_q[WPB][SPW][LL];

    const int b = blockIdx.y;
    load_tables(g_pack + b * NS, g_lrc + b * NS, capf + b * NS, s_pack, s_lrc);
    __syncthreads();

    const int wid = threadIdx.x >> 6;
    const int lane = threadIdx.x & 63;
    const int base = blockIdx.x * (WPB * SPW);
    const int sA = base + wid;
    const int sB = base + WPB + wid;

    const float* db = dist + b * LL * LL;
    unsigned long long ubA0, ubA1, ubB0, ubB1;
    {
        unsigned long long ub[2];
        span_prologue(db, s_pack[sA], lane, s_q[wid][0], ub);
        ubA0 = ub[0]; ubA1 = ub[1];
        span_prologue(db, s_pack[sB], lane, s_q[wid][1], ub);
        ubB0 = ub[0]; ubB1 = ub[1];
    }
    uint32_t lrcA = s_lrc[sA], lrcB = s_lrc[sB];
    int lsA = lrcA & 127, rsA = (lrcA >> 7) & 127;
    int lsB = lrcB & 127, rsB = (lrcB >> 7) & 127;
    const float* qa = s_q[wid][0];
    const float* qb = s_q[wid][1];

    unsigned vA = 0u, vB = 0u; int viA = -1, viB = -1; unsigned tauA = 0u, tauB = 0u;

    for (int t0 = 0; t0 < NS; t0 += 64) {
        int t = t0 + lane;
        unsigned keyA = 0u, keyB = 0u;
        if (t < NS) {
            float4 pt = s_pack[t];
            uint32_t rt = __float_as_uint(pt.w);
            int i0 = rt & 127, i1 = (rt >> 8) & 127, i2 = (rt >> 16) & 127;
            uint32_t lr = s_lrc[t];
            int lt = lr & 127, rt2 = (lr >> 7) & 127;
            int ri0 = rt >> 24;
            bool capb = ((lr >> 14) & 1u) != 0;
            {   // span A
                float g = __fmaf_rn(pt.x, qa[i0], 0.0f);
                g = __fmaf_rn(pt.y, qa[i1], g);
                g = __fmaf_rn(pt.z, qa[i2], g);
                int dl = lt - lsA; if (dl < 0) dl = -dl;
                int dr = rt2 - rsA; if (dr < 0) dr = -dr;
                bool neq = (t != sA);
                bool geom = neq && (dl <= 1) && (dr <= 1);
                unsigned long long bits = (ri0 & 64) ? ubA1 : ubA0;
                bool um = (((bits >> (ri0 & 63)) & 1ull) != 0) && capb && neq;
                if (um || geom) keyA = __float_as_uint(g);   // gate >= 0 -> monotone u32
            }
            {   // span B
                float g = __fmaf_rn(pt.x, qb[i0], 0.0f);
                g = __fmaf_rn(pt.y, qb[i1], g);
                g = __fmaf_rn(pt.z, qb[i2], g);
                int dl = lt - lsB; if (dl < 0) dl = -dl;
                int dr = rt2 - rsB; if (dr < 0) dr = -dr;
                bool neq = (t != sB);
                bool geom = neq && (dl <= 1) && (dr <= 1);
                unsigned long long bits = (ri0 & 64) ? ubB1 : ubB0;
                bool um = (((bits >> (ri0 & 63)) & 1ull) != 0) && capb && neq;
                if (um || geom) keyB = __float_as_uint(g);
            }
        }
        topk_merge(keyA, t0, lane, vA, viA, tauA);
        topk_merge(keyB, t0, lane, vB, viB, tauB);
    }

    span_epilogue(vA, viA, b, sA, lane, rowflag, out);
    span_epilogue(vB, viB, b, sB, lane, rowflag, out);
}

// Kernel B: slow path — exact numpy argsort(gate)[::-1][:K] for flagged rows.
__global__ __launch_bounds__(256)
void span_slow_kernel(const float4* __restrict__ g_pack,
                      const uint16_t* __restrict__ g_lrc,
                      const float* __restrict__ dist,
                      const unsigned char* __restrict__ capf,
                      const unsigned char* __restrict__ rowflag,
                      int* __restrict__ out) {
    __shared__ int s_nrows;
    __shared__ int s_rows[256];
    __shared__ float4 s_pack[NS];
    __shared__ uint16_t s_lrc[NS];
    __shared__ float s_qq[LL];
    __shared__ unsigned long long s_cov[2];
    __shared__ unsigned long long s_buf[NS];
    __shared__ int s_posL[NS], s_posR[NS];
    __shared__ int s_stk[48];

    const int b = blockIdx.x;
    if (threadIdx.x == 0) s_nrows = 0;
    __syncthreads();
    for (int i = threadIdx.x; i < NS; i += 256) {
        if (rowflag[b * NS + i]) {
            int k = atomicAdd(&s_nrows, 1);
            if (k < 256) s_rows[k] = i;
        }
    }
    __syncthreads();
    int nrows = s_nrows; if (nrows > 256) nrows = 256;
    if (nrows == 0) return;

    load_tables(g_pack + b * NS, g_lrc + b * NS, capf + b * NS, s_pack, s_lrc);
    __syncthreads();

    const int wid = threadIdx.x >> 6;
    const int lane = threadIdx.x & 63;
    const float* db = dist + b * LL * LL;

    for (int ri = 0; ri < nrows; ++ri) {
        const int s = s_rows[ri];
        uint32_t lrc = s_lrc[s];
        int ls = lrc & 127, rs = (lrc >> 7) & 127;

        if (wid == 0) {   // wave 0: q row + coverage ballots
            unsigned long long ub[2];
            span_prologue(db, s_pack[s], lane, s_qq, ub);
            if (lane == 0) { s_cov[0] = ub[0]; s_cov[1] = ub[1]; }
        }
        __syncthreads();
        unsigned long long ub0 = s_cov[0], ub1 = s_cov[1];

        for (int t = threadIdx.x; t < NS; t += 256) {   // all threads: gate fill
            float4 pt = s_pack[t];
            uint32_t rt = __float_as_uint(pt.w);
            float g = __fmaf_rn(pt.x, s_qq[rt & 127], 0.0f);
            g = __fmaf_rn(pt.y, s_qq[(rt >> 8) & 127], g);
            g = __fmaf_rn(pt.z, s_qq[(rt >> 16) & 127], g);
            uint32_t lr = s_lrc[t];
            int lt = lr & 127, rt2 = (lr >> 7) & 127;
            int dl = lt - ls; if (dl < 0) dl = -dl;
            int dr = rt2 - rs; if (dr < 0) dr = -dr;
            bool neq = (t != s);
            bool geom = neq && (dl <= 1) && (dr <= 1);
            int ri0 = rt >> 24;
            unsigned long long bits = (ri0 & 64) ? ub1 : ub0;
            bool um = (((bits >> (ri0 & 63)) & 1ull) != 0) && ((lr >> 14) & 1u) && neq;
            unsigned h32 = (um || geom) ? __float_as_uint(g) : 0xFF800000u;  // -inf
            s_buf[t] = ((unsigned long long)h32 << 32) | (unsigned)t;
        }
        __syncthreads();

        if (wid == 0) {
            wave_np_sort_top(s_buf, NS, lane, s_stk, s_posL, s_posR);
            if (lane < NK) {
                unsigned long long k = s_buf[NS - 1 - lane];  // reversed ascending
                int idx = ((unsigned)(k >> 32) == 0xFF800000u) ? s : (int)(k & 0xffffffffull);
                out[(b * NS + s) * NK + lane] = idx;
            }
        }
        __syncthreads();
    }
}

extern "C" void kernel_launch(void* const* d_in, const int* in_sizes, int n_in,
                              void* d_out, int out_size, void* d_ws, size_t ws_size,
                              hipStream_t stream) {
    const int* hi = (const int*)d_in[0];
    const float* hw = (const float*)d_in[1];
    const float* dist = (const float*)d_in[2];
    int* out = (int*)d_out;

    unsigned char* ws = (unsigned char*)d_ws;
    unsigned char* top1 = ws;                              // NB*NS
    unsigned char* capf = ws + NB * NS;                    // NB*NS
    unsigned char* rowflag = ws + 2 * NB * NS;             // NB*NS
    float4* g_pack = (float4*)(ws + 3 * NB * NS);          // NB*NS*16 (offset 46272, 16-aligned)
    uint16_t* g_lrc = (uint16_t*)(ws + 3 * NB * NS + NB * NS * 16);  // NB*NS*2

    build_tables_kernel<<<(NB * LL * 16) / 256, 256, 0, stream>>>(hi, hw, g_pack, g_lrc, top1);
    cap_kernel<<<(NB * LL * 64) / 256, 256, 0, stream>>>(top1, capf);
    dim3 grid(NS / (WPB * SPW), NB);
    span_scan_kernel<<<grid, 256, 0, stream>>>(g_pack, g_lrc, dist, capf, rowflag, out);
    span_slow_kernel<<<NB, 256, 0, stream>>>(g_pack, g_lrc, dist, capf, rowflag, out);
}

// Round 2
// 212.790 us; speedup vs baseline: 1.1257x; 1.0061x over previous
//
#include <hip/hip_runtime.h>
#include <stdint.h>

#define NB 8
#define LL 128
#define NS 1928      // number of spans (l,r), r-l+1 <= 16
#define NK 10        // top-k
#define WPB 4        // waves per block
#define SPW 2        // spans per wave
#define SLOTS 32     // slow-path parallel slots per batch

// span id for (l, r): offset(l) + (r-l)
__device__ __forceinline__ int span_id(int l, int r) {
    int off = (l <= 112) ? (l << 4) : (NS - (((128 - l) * (129 - l)) >> 1));
    return off + (r - l);
}

// Replica of numpy's SIMD float32 exp (verified exact vs oracle in R9/R10).
__device__ __forceinline__ float npexp_f32(float x) {
    const float magic = 12582912.0f;
    const float log2e = 1.442695040888963f;
    const float c1 = -6.93145752e-1f;
    const float c2 = -1.42860677e-6f;
    float t = __fmul_rn(x, log2e);
    float q = __fsub_rn(__fadd_rn(t, magic), magic);
    float r = __fmaf_rn(q, c1, x);
    r = __fmaf_rn(q, c2, r);
    float num = __fmaf_rn(r, 5.082762527590693718096e-04f, 6.757896990527504603057e-03f);
    num = __fmaf_rn(num, r, 5.114512081637298353406e-02f);
    num = __fmaf_rn(num, r, 2.473615434895520810817e-01f);
    num = __fmaf_rn(num, r, 7.257664613233124478488e-01f);
    num = __fmaf_rn(num, r, 9.999999999980870924916e-01f);
    float den = __fmaf_rn(r, 2.159509375685829852307e-02f, -2.742335390411667452936e-01f);
    den = __fmaf_rn(den, r, 1.0f);
    float p = __fdiv_rn(num, den);
    int qi = (int)q;
    return __fmul_rn(p, __int_as_float((127 + qi) << 23));
}

__device__ __forceinline__ float keyval(unsigned long long k) {
    return __uint_as_float((unsigned)(k >> 32));
}

__device__ __forceinline__ void wfence() {
    __builtin_amdgcn_wave_barrier();
    __threadfence_block();
    __builtin_amdgcn_wave_barrier();
}

// Wave-parallel numpy-aquicksort partition (R10-verified semantics), fast form.
__device__ int wave_partition_fast(unsigned long long* a, int* posL, int* posR,
                                   int pl, int pr, int lane) {
    int pm = pl + ((pr - pl) >> 1);
    unsigned long long vl = a[pl], vm = a[pm], vr = a[pr], tt;
    if (keyval(vm) < keyval(vl)) { tt = vm; vm = vl; vl = tt; }
    if (keyval(vr) < keyval(vm)) { tt = vr; vr = vm; vm = tt; }
    if (keyval(vm) < keyval(vl)) { tt = vm; vm = vl; vl = tt; }
    float vp = keyval(vm);
    unsigned long long vq = a[pr - 1];
    if (lane == 0) { a[pl] = vl; a[pr] = vr; a[pm] = vq; a[pr - 1] = vm; }
    wfence();

    unsigned long long lmask = (1ull << lane) - 1ull;
    int baseL = 0, baseR = 0;
    for (int p0 = pl; p0 <= pr; p0 += 64) {
        int pos = p0 + lane;
        bool inr = (pos <= pr);
        float v = inr ? keyval(a[pos]) : 0.0f;
        bool ge = inr && (pos > pl) && (pos < pr) && (v >= vp);
        bool le = inr && (pos <= pr - 2) && (v <= vp);
        unsigned long long bge = __ballot(ge);
        unsigned long long ble = __ballot(le);
        if (ge) posL[baseL + __popcll(bge & lmask)] = pos;
        if (le) posR[baseR + __popcll(ble & lmask)] = pos;
        baseL += __popcll(bge);
        baseR += __popcll(ble);
    }
    wfence();
    int totGE = baseL, totLE = baseR;
    int maxk = (totGE < totLE) ? totGE : totLE;
    int K = 0;
    for (int base = 0;; base += 64) {
        int k = base + lane;
        bool active = (k < maxk);
        int Lk = active ? posL[k] : 0x7fffffff;
        int Rk = active ? posR[totLE - 1 - k] : -1;
        bool sw = active && (Lk < Rk);
        unsigned long long bm = __ballot(sw);     // monotone prefix of true
        int nsw = (~bm == 0ull) ? 64 : (__ffsll((long long)~bm) - 1);
        if (sw && (lane < nsw)) {
            unsigned long long tl = a[Lk], tr = a[Rk];
            a[Lk] = tr; a[Rk] = tl;              // all swapped positions distinct (proof R10)
        }
        K += nsw;
        if (nsw < 64) break;
    }
    wfence();
    int pi = posL[K];                             // K < totGE (pivot at pr-1 never swapped)
    if (K > 0) { int rp = posR[totLE - K]; if (rp < pi) pi = rp; }
    if (lane == 0) { tt = a[pi]; a[pi] = a[pr - 1]; a[pr - 1] = tt; }
    wfence();
    return pi;
}

__device__ __forceinline__ void lane_sift(unsigned long long* h, int start, int hm) {
    unsigned long long tmp = h[start];
    int i = start, j = start + start;
    while (j <= hm) {
        if (j < hm && keyval(h[j]) < keyval(h[j + 1])) ++j;
        if (keyval(tmp) < keyval(h[j])) { h[i] = h[j]; i = j; j += j; }
        else break;
    }
    h[i] = tmp;
}

// numpy aheapsort on a[lo..hi], extracting only positions >= needlo.
__device__ void wave_heap_top(unsigned long long* a, int lo, int hi, int needlo, int lane) {
    unsigned long long* h = a + lo - 1;
    int hm = hi - lo + 1;
    int half = hm >> 1;
    int maxlvl = 0; { int v = half; while (v >>= 1) ++maxlvl; }
    for (int lvl = maxlvl; lvl >= 0; --lvl) {
        int n0 = 1 << lvl;
        int n1 = (n0 << 1) - 1; if (n1 > half) n1 = half;
        for (int nb = n0; nb <= n1; nb += 64) {
            int node = nb + lane;
            if (node <= n1) lane_sift(h, node, hm);
        }
        wfence();
    }
    int E = hi - needlo + 1;
    if (E > hm - 1) E = hm - 1;
    if (lane == 0) {
        int m = hm;
        for (int e = 0; e < E; ++e) {
            unsigned long long tmp = h[m]; h[m] = h[1]; --m;
            int i = 1, j = 2;
            while (j <= m) {
                if (j < m && keyval(h[j]) < keyval(h[j + 1])) ++j;
                if (keyval(tmp) < keyval(h[j])) { h[i] = h[j]; i = j; j += j; }
                else break;
            }
            h[i] = tmp;
        }
    }
    wfence();
}

// stable insertion-sort outcome via parallel stable rank (len <= 16)
__device__ void wave_insertion(unsigned long long* a, int lo, int hi, int lane) {
    int len = hi - lo + 1;
    unsigned long long v = (lane < len) ? a[lo + lane] : 0ull;
    float fv = keyval(v);
    int rank = 0;
    for (int j = 0; j < len; ++j) {
        unsigned long long vj = __shfl(v, j, 64);
        float fj = keyval(vj);
        if ((fj < fv) || (fj == fv && j < lane)) ++rank;
    }
    wfence();
    if (lane < len) a[lo + rank] = v;
    wfence();
}

// numpy introsort (verified semantics: GLOBAL depth budget, SMALL=15,
// push-larger/continue-smaller), computing only positions >= n-NK exactly.
__device__ void wave_np_sort_top(unsigned long long* a, int n, int lane, int* stk,
                                 int* posL, int* posR) {
    int depth = 0; { int v = n; while (v >>= 1) ++depth; }
    depth *= 2;
    const int TOPLO = n - NK;
    int sp = 0;
    int lo = 0, hi = n - 1;
    for (;;) {
        while (hi - lo > 15) {
            if (depth-- < 0) {
                if (hi >= TOPLO) wave_heap_top(a, lo, hi, (lo > TOPLO ? lo : TOPLO), lane);
                goto pop;
            }
            {
                int pi = wave_partition_fast(a, posL, posR, lo, hi, lane);
                if (pi - lo < hi - pi) {
                    if (lane == 0) { stk[sp * 2] = pi + 1; stk[sp * 2 + 1] = hi; }
                    ++sp; hi = pi - 1;
                } else {
                    if (lane == 0) { stk[sp * 2] = lo; stk[sp * 2 + 1] = pi - 1; }
                    ++sp; lo = pi + 1;
                }
                wfence();
            }
        }
        if (hi > lo && hi >= TOPLO) wave_insertion(a, lo, hi, lane);
pop:
        if (sp == 0) break;
        --sp;
        lo = stk[sp * 2]; hi = stk[sp * 2 + 1];
    }
}

// Kernel 1: build packed tables ONCE per batch, fused with top1 extraction.
__global__ __launch_bounds__(256)
void build_tables_kernel(const int* __restrict__ hi, const float* __restrict__ hw,
                         float4* __restrict__ g_pack, uint16_t* __restrict__ g_lrc,
                         unsigned char* __restrict__ top1) {
    int j = blockIdx.x * 256 + threadIdx.x;
    if (j >= NB * LL * 16) return;
    int b = j >> 11;                 // LL*16 = 2048
    int lw = j & 2047;
    int l = lw >> 4, w = lw & 15, r = l + w;
    if (r >= LL) return;
    int sid = span_id(l, r);
    const int* hb = hi + b * LL * LL * 4;
    const float* wb = hw + b * LL * LL * 4;
    int4 iv = *(const int4*)(hb + (l * LL + r) * 4);
    float4 wv = *(const float4*)(wb + (l * LL + r) * 4);
    int ia = iv.x, ib = iv.y, ic = iv.z;
    float wa = wv.x, wb2 = wv.y, wc = wv.z;
    int m0, m1 = 255, m2 = 255;
    float W0, W1 = 0.f, W2 = 0.f;
    if (ia == ib && ib == ic) {
        m0 = ia; W0 = __fadd_rn(__fadd_rn(wa, wb2), wc);
    } else if (ia == ib) {
        float W = __fadd_rn(wa, wb2);
        if (ia < ic) { m0 = ia; W0 = W; m1 = ic; W1 = wc; }
        else         { m0 = ic; W0 = wc; m1 = ia; W1 = W; }
    } else if (ia == ic) {
        float W = __fadd_rn(wa, wc);
        if (ia < ib) { m0 = ia; W0 = W; m1 = ib; W1 = wb2; }
        else         { m0 = ib; W0 = wb2; m1 = ia; W1 = W; }
    } else if (ib == ic) {
        float W = __fadd_rn(wb2, wc);
        if (ia < ib) { m0 = ia; W0 = wa; m1 = ib; W1 = W; }
        else         { m0 = ib; W0 = W; m1 = ia; W1 = wa; }
    } else {
        int x0 = ia, x1 = ib, x2 = ic; float y0 = wa, y1 = wb2, y2 = wc;
        if (x0 > x1) { int tx = x0; x0 = x1; x1 = tx; float ty = y0; y0 = y1; y1 = ty; }
        if (x1 > x2) { int tx = x1; x1 = x2; x2 = tx; float ty = y1; y1 = y2; y2 = ty; }
        if (x0 > x1) { int tx = x0; x0 = x1; x1 = tx; float ty = y0; y0 = y1; y1 = ty; }
        m0 = x0; m1 = x1; m2 = x2; W0 = y0; W1 = y1; W2 = y2;
    }
    uint32_t rec = (uint32_t)m0 | ((uint32_t)m1 << 8) | ((uint32_t)m2 << 16)
                 | ((uint32_t)(ia & 127) << 24);
    g_pack[b * NS + sid] = make_float4(W0, W1, W2, __uint_as_float(rec));
    g_lrc[b * NS + sid] = (uint16_t)(l | (r << 7));
    top1[b * NS + sid] = (unsigned char)(ia & 127);
}

// Kernel 2: one wave per (b,l) — cumsum cap.
__global__ void cap_kernel(const unsigned char* __restrict__ top1,
                           unsigned char* __restrict__ flags) {
    int gw = (blockIdx.x * blockDim.x + threadIdx.x) >> 6;
    int lane = threadIdx.x & 63;
    int b = gw >> 7, l = gw & 127;
    const unsigned char* tb = top1 + b * NS;
    unsigned char* fb = flags + b * NS;
    int cnt = 0;
    for (int t0 = 0; t0 < NS; t0 += 64) {
        int t = t0 + lane;
        int tp = (t < NS) ? (int)tb[t] : 255;
        bool match = (tp == l);
        unsigned long long m = __ballot(match);
        if (match) {
            int pre = __popcll(m & ((1ull << lane) - 1ull));
            fb[t] = (cnt + pre + 1 <= 128) ? 1 : 0;
        }
        cnt += __popcll(m);
    }
}

// Cheap global->LDS table staging, OR-ing cap bit.
__device__ __forceinline__ void load_tables(const float4* __restrict__ gp,
                                            const uint16_t* __restrict__ gl,
                                            const unsigned char* __restrict__ fb,
                                            float4* s_pack, uint16_t* s_lrc) {
    for (int j = threadIdx.x; j < NS; j += 256) {
        s_pack[j] = gp[j];
        s_lrc[j] = (uint16_t)(gl[j] | ((fb[j] & 1) << 14));
    }
}

// Per-span prologue: q row (wave-wide, 128 entries) + coverage ballots.
__device__ __forceinline__ void span_prologue(const float* __restrict__ db, float4 ps,
                                              int lane, float* qrow,
                                              unsigned long long* ub) {
    uint32_t rec = __float_as_uint(ps.w);
    int m0 = rec & 255, m1 = (rec >> 8) & 255, m2 = (rec >> 16) & 255;
    bool e1 = (m1 != 255), e2 = (m2 != 255);
    const float* row0 = db + m0 * LL;
    const float* row1 = db + (e1 ? m1 : 0) * LL;
    const float* row2 = db + (e2 ? m2 : 0) * LL;
    int mA = lane, mB = lane + 64;
    float dA0 = row0[mA], dB0 = row0[mB];
    float dA1 = row1[mA], dB1 = row1[mB];
    float dA2 = row2[mA], dB2 = row2[mB];
    float qA = __fmaf_rn(ps.x, npexp_f32(-dA0), 0.0f);
    qA = __fmaf_rn(ps.y, npexp_f32(-dA1), qA);
    qA = __fmaf_rn(ps.z, npexp_f32(-dA2), qA);
    float qB = __fmaf_rn(ps.x, npexp_f32(-dB0), 0.0f);
    qB = __fmaf_rn(ps.y, npexp_f32(-dB1), qB);
    qB = __fmaf_rn(ps.z, npexp_f32(-dB2), qB);
    bool cA = (dA0 <= 2.0f || mA == m0) ||
              (e1 && (dA1 <= 2.0f || mA == m1)) ||
              (e2 && (dA2 <= 2.0f || mA == m2));
    bool cB = (dB0 <= 2.0f || mB == m0) ||
              (e1 && (dB1 <= 2.0f || mB == m1)) ||
              (e2 && (dB2 <= 2.0f || mB == m2));
    ub[0] = __ballot(cA);
    ub[1] = __ballot(cB);
    qrow[mA] = qA;
    qrow[mB] = qB;
}

// Sorted top-11 merge step (bit-identical semantics to R10-verified version).
__device__ __forceinline__ void topk_merge(unsigned key, int t0, int lane,
                                           unsigned& v, int& vi, unsigned& tau) {
    unsigned long long bm = __ballot(key > tau);
    while (bm) {
        int ln = __ffsll((long long)bm) - 1;
        bm &= bm - 1;
        unsigned kk = __shfl(key, ln, 64);
        if (kk > tau) {                    // wave-uniform
            int tk = t0 + ln;
            unsigned vprev = __shfl_up(v, 1, 64);
            int iprev = __shfl_up(vi, 1, 64);
            if (lane == 0) vprev = 0xFFFFFFFFu;
            bool keep = (v >= kk);         // equals keep -> new after (asc-t among ties)
            bool fp = (vprev < kk);
            v = keep ? v : (fp ? vprev : kk);
            vi = keep ? vi : (fp ? iprev : tk);
            tau = __shfl(v, 10, 64);
        }
    }
}

__device__ __forceinline__ void span_epilogue(unsigned v, int vi, int b, int s, int lane,
                                              unsigned char* __restrict__ rowflag,
                                              int* __restrict__ out) {
    unsigned vn = __shfl_down(v, 1, 64);
    bool tie = (lane < NK) && (v != 0u) && (vn == v);
    bool flag = (__ballot(tie) != 0ull);
    if (lane < NK) {
        int o = (b * NS + s) * NK + lane;
        out[NB * NS * NK + o] = 1;             // N_mask = ones always
        if (!flag) out[o] = (vi >= 0) ? vi : s;
    }
    if (lane == 0) rowflag[b * NS + s] = flag ? 1 : 0;
}

// Kernel A: fast path — 2 spans per wave, shared candidate decode.
__global__ __launch_bounds__(256)
void span_scan_kernel(const float4* __restrict__ g_pack,
                      const uint16_t* __restrict__ g_lrc,
                      const float* __restrict__ dist,
                      const unsigned char* __restrict__ capf,
                      unsigned char* __restrict__ rowflag,
                      int* __restrict__ out) {
    __shared__ float4 s_pack[NS];
    __shared__ uint16_t s_lrc[NS];
    __shared__ float s_q[WPB][SPW][LL];

    const int b = blockIdx.y;
    load_tables(g_pack + b * NS, g_lrc + b * NS, capf + b * NS, s_pack, s_lrc);
    __syncthreads();

    const int wid = threadIdx.x >> 6;
    const int lane = threadIdx.x & 63;
    const int base = blockIdx.x * (WPB * SPW);
    const int sA = base + wid;
    const int sB = base + WPB + wid;

    const float* db = dist + b * LL * LL;
    unsigned long long ubA0, ubA1, ubB0, ubB1;
    {
        unsigned long long ub[2];
        span_prologue(db, s_pack[sA], lane, s_q[wid][0], ub);
        ubA0 = ub[0]; ubA1 = ub[1];
        span_prologue(db, s_pack[sB], lane, s_q[wid][1], ub);
        ubB0 = ub[0]; ubB1 = ub[1];
    }
    uint32_t lrcA = s_lrc[sA], lrcB = s_lrc[sB];
    int lsA = lrcA & 127, rsA = (lrcA >> 7) & 127;
    int lsB = lrcB & 127, rsB = (lrcB >> 7) & 127;
    const float* qa = s_q[wid][0];
    const float* qb = s_q[wid][1];

    unsigned vA = 0u, vB = 0u; int viA = -1, viB = -1; unsigned tauA = 0u, tauB = 0u;

    for (int t0 = 0; t0 < NS; t0 += 64) {
        int t = t0 + lane;
        unsigned keyA = 0u, keyB = 0u;
        if (t < NS) {
            float4 pt = s_pack[t];
            uint32_t rt = __float_as_uint(pt.w);
            int i0 = rt & 127, i1 = (rt >> 8) & 127, i2 = (rt >> 16) & 127;
            uint32_t lr = s_lrc[t];
            int lt = lr & 127, rt2 = (lr >> 7) & 127;
            int ri0 = rt >> 24;
            bool capb = ((lr >> 14) & 1u) != 0;
            {   // span A
                float g = __fmaf_rn(pt.x, qa[i0], 0.0f);
                g = __fmaf_rn(pt.y, qa[i1], g);
                g = __fmaf_rn(pt.z, qa[i2], g);
                int dl = lt - lsA; if (dl < 0) dl = -dl;
                int dr = rt2 - rsA; if (dr < 0) dr = -dr;
                bool neq = (t != sA);
                bool geom = neq && (dl <= 1) && (dr <= 1);
                unsigned long long bits = (ri0 & 64) ? ubA1 : ubA0;
                bool um = (((bits >> (ri0 & 63)) & 1ull) != 0) && capb && neq;
                if (um || geom) keyA = __float_as_uint(g);   // gate >= 0 -> monotone u32
            }
            {   // span B
                float g = __fmaf_rn(pt.x, qb[i0], 0.0f);
                g = __fmaf_rn(pt.y, qb[i1], g);
                g = __fmaf_rn(pt.z, qb[i2], g);
                int dl = lt - lsB; if (dl < 0) dl = -dl;
                int dr = rt2 - rsB; if (dr < 0) dr = -dr;
                bool neq = (t != sB);
                bool geom = neq && (dl <= 1) && (dr <= 1);
                unsigned long long bits = (ri0 & 64) ? ubB1 : ubB0;
                bool um = (((bits >> (ri0 & 63)) & 1ull) != 0) && capb && neq;
                if (um || geom) keyB = __float_as_uint(g);
            }
        }
        topk_merge(keyA, t0, lane, vA, viA, tauA);
        topk_merge(keyB, t0, lane, vB, viB, tauB);
    }

    span_epilogue(vA, viA, b, sA, lane, rowflag, out);
    span_epilogue(vB, viB, b, sB, lane, rowflag, out);
}

// Kernel B: slow path — exact numpy argsort(gate)[::-1][:K] for flagged rows.
// Parallelized: grid (NB, SLOTS); slot y handles flagged rows i with i % SLOTS == y,
// in ascending i order (rows are fully independent).
__global__ __launch_bounds__(256)
void span_slow_kernel(const float4* __restrict__ g_pack,
                      const uint16_t* __restrict__ g_lrc,
                      const float* __restrict__ dist,
                      const unsigned char* __restrict__ capf,
                      const unsigned char* __restrict__ rowflag,
                      int* __restrict__ out) {
    __shared__ int s_nrows;
    __shared__ int s_rows[64];          // ceil(NS/SLOTS) = 61 max
    __shared__ float4 s_pack[NS];
    __shared__ uint16_t s_lrc[NS];
    __shared__ float s_qq[LL];
    __shared__ unsigned long long s_cov[2];
    __shared__ unsigned long long s_buf[NS];
    __shared__ int s_posL[NS], s_posR[NS];
    __shared__ int s_stk[48];

    const int b = blockIdx.x;
    const int slot = blockIdx.y;
    const unsigned char* rf = rowflag + b * NS;

    // wave 0 compacts this slot's flagged rows (ascending)
    if (threadIdx.x < 64) {
        int lane = threadIdx.x;
        int i = slot + lane * SLOTS;
        bool f = (i < NS) && (rf[i] != 0);
        unsigned long long m = __ballot(f);
        if (f) s_rows[__popcll(m & ((1ull << lane) - 1ull))] = i;
        if (lane == 0) s_nrows = __popcll(m);
    }
    __syncthreads();
    int nrows = s_nrows;
    if (nrows == 0) return;

    load_tables(g_pack + b * NS, g_lrc + b * NS, capf + b * NS, s_pack, s_lrc);
    __syncthreads();

    const int wid = threadIdx.x >> 6;
    const int lane = threadIdx.x & 63;
    const float* db = dist + b * LL * LL;

    for (int ri = 0; ri < nrows; ++ri) {
        const int s = s_rows[ri];
        uint32_t lrc = s_lrc[s];
        int ls = lrc & 127, rs = (lrc >> 7) & 127;

        if (wid == 0) {   // wave 0: q row + coverage ballots
            unsigned long long ub[2];
            span_prologue(db, s_pack[s], lane, s_qq, ub);
            if (lane == 0) { s_cov[0] = ub[0]; s_cov[1] = ub[1]; }
        }
        __syncthreads();
        unsigned long long ub0 = s_cov[0], ub1 = s_cov[1];

        for (int t = threadIdx.x; t < NS; t += 256) {   // all threads: gate fill
            float4 pt = s_pack[t];
            uint32_t rt = __float_as_uint(pt.w);
            float g = __fmaf_rn(pt.x, s_qq[rt & 127], 0.0f);
            g = __fmaf_rn(pt.y, s_qq[(rt >> 8) & 127], g);
            g = __fmaf_rn(pt.z, s_qq[(rt >> 16) & 127], g);
            uint32_t lr = s_lrc[t];
            int lt = lr & 127, rt2 = (lr >> 7) & 127;
            int dl = lt - ls; if (dl < 0) dl = -dl;
            int dr = rt2 - rs; if (dr < 0) dr = -dr;
            bool neq = (t != s);
            bool geom = neq && (dl <= 1) && (dr <= 1);
            int ri0 = rt >> 24;
            unsigned long long bits = (ri0 & 64) ? ub1 : ub0;
            bool um = (((bits >> (ri0 & 63)) & 1ull) != 0) && ((lr >> 14) & 1u) && neq;
            unsigned h32 = (um || geom) ? __float_as_uint(g) : 0xFF800000u;  // -inf
            s_buf[t] = ((unsigned long long)h32 << 32) | (unsigned)t;
        }
        __syncthreads();

        if (wid == 0) {
            wave_np_sort_top(s_buf, NS, lane, s_stk, s_posL, s_posR);
            if (lane < NK) {
                unsigned long long k = s_buf[NS - 1 - lane];  // reversed ascending
                int idx = ((unsigned)(k >> 32) == 0xFF800000u) ? s : (int)(k & 0xffffffffull);
                out[(b * NS + s) * NK + lane] = idx;
            }
        }
        __syncthreads();
    }
}

extern "C" void kernel_launch(void* const* d_in, const int* in_sizes, int n_in,
                              void* d_out, int out_size, void* d_ws, size_t ws_size,
                              hipStream_t stream) {
    const int* hi = (const int*)d_in[0];
    const float* hw = (const float*)d_in[1];
    const float* dist = (const float*)d_in[2];
    int* out = (int*)d_out;

    unsigned char* ws = (unsigned char*)d_ws;
    unsigned char* top1 = ws;                              // NB*NS
    unsigned char* capf = ws + NB * NS;                    // NB*NS
    unsigned char* rowflag = ws + 2 * NB * NS;             // NB*NS
    float4* g_pack = (float4*)(ws + 3 * NB * NS);          // NB*NS*16 (offset 46272, 16-aligned)
    uint16_t* g_lrc = (uint16_t*)(ws + 3 * NB * NS + NB * NS * 16);  // NB*NS*2

    build_tables_kernel<<<(NB * LL * 16) / 256, 256, 0, stream>>>(hi, hw, g_pack, g_lrc, top1);
    cap_kernel<<<(NB * LL * 64) / 256, 256, 0, stream>>>(top1, capf);
    dim3 grid(NS / (WPB * SPW), NB);
    span_scan_kernel<<<grid, 256, 0, stream>>>(g_pack, g_lrc, dist, capf, rowflag, out);
    dim3 sgrid(NB, SLOTS);
    span_slow_kernel<<<sgrid, 256, 0, stream>>>(g_pack, g_lrc, dist, capf, rowflag, out);
}

// Round 4
// 199.361 us; speedup vs baseline: 1.2015x; 1.0674x over previous
//
#include <hip/hip_runtime.h>
#include <stdint.h>

#define NB 8
#define LL 128
#define NS 1928      // number of spans (l,r), r-l+1 <= 16
#define NK 10        // top-k
#define WPB 4        // waves per block
#define SPW 2        // spans per wave
#define SLOTS 32     // slow-path parallel slots per batch

// span id for (l, r): offset(l) + (r-l)
__device__ __forceinline__ int span_id(int l, int r) {
    int off = (l <= 112) ? (l << 4) : (NS - (((128 - l) * (129 - l)) >> 1));
    return off + (r - l);
}

// Replica of numpy's SIMD float32 exp (verified exact vs oracle in R9/R10).
__device__ __forceinline__ float npexp_f32(float x) {
    const float magic = 12582912.0f;
    const float log2e = 1.442695040888963f;
    const float c1 = -6.93145752e-1f;
    const float c2 = -1.42860677e-6f;
    float t = __fmul_rn(x, log2e);
    float q = __fsub_rn(__fadd_rn(t, magic), magic);
    float r = __fmaf_rn(q, c1, x);
    r = __fmaf_rn(q, c2, r);
    float num = __fmaf_rn(r, 5.082762527590693718096e-04f, 6.757896990527504603057e-03f);
    num = __fmaf_rn(num, r, 5.114512081637298353406e-02f);
    num = __fmaf_rn(num, r, 2.473615434895520810817e-01f);
    num = __fmaf_rn(num, r, 7.257664613233124478488e-01f);
    num = __fmaf_rn(num, r, 9.999999999980870924916e-01f);
    float den = __fmaf_rn(r, 2.159509375685829852307e-02f, -2.742335390411667452936e-01f);
    den = __fmaf_rn(den, r, 1.0f);
    float p = __fdiv_rn(num, den);
    int qi = (int)q;
    return __fmul_rn(p, __int_as_float((127 + qi) << 23));
}

__device__ __forceinline__ float keyval(unsigned long long k) {
    return __uint_as_float((unsigned)(k >> 32));
}

__device__ __forceinline__ void wfence() {
    __builtin_amdgcn_wave_barrier();
    __threadfence_block();
    __builtin_amdgcn_wave_barrier();
}

// Wave-parallel numpy-aquicksort partition (R10-verified semantics), fast form.
__device__ int wave_partition_fast(unsigned long long* a, int* posL, int* posR,
                                   int pl, int pr, int lane) {
    int pm = pl + ((pr - pl) >> 1);
    unsigned long long vl = a[pl], vm = a[pm], vr = a[pr], tt;
    if (keyval(vm) < keyval(vl)) { tt = vm; vm = vl; vl = tt; }
    if (keyval(vr) < keyval(vm)) { tt = vr; vr = vm; vm = tt; }
    if (keyval(vm) < keyval(vl)) { tt = vm; vm = vl; vl = tt; }
    float vp = keyval(vm);
    unsigned long long vq = a[pr - 1];
    if (lane == 0) { a[pl] = vl; a[pr] = vr; a[pm] = vq; a[pr - 1] = vm; }
    wfence();

    unsigned long long lmask = (1ull << lane) - 1ull;
    int baseL = 0, baseR = 0;
    for (int p0 = pl; p0 <= pr; p0 += 64) {
        int pos = p0 + lane;
        bool inr = (pos <= pr);
        float v = inr ? keyval(a[pos]) : 0.0f;
        bool ge = inr && (pos > pl) && (pos < pr) && (v >= vp);
        bool le = inr && (pos <= pr - 2) && (v <= vp);
        unsigned long long bge = __ballot(ge);
        unsigned long long ble = __ballot(le);
        if (ge) posL[baseL + __popcll(bge & lmask)] = pos;
        if (le) posR[baseR + __popcll(ble & lmask)] = pos;
        baseL += __popcll(bge);
        baseR += __popcll(ble);
    }
    wfence();
    int totGE = baseL, totLE = baseR;
    int maxk = (totGE < totLE) ? totGE : totLE;
    int K = 0;
    for (int base = 0;; base += 64) {
        int k = base + lane;
        bool active = (k < maxk);
        int Lk = active ? posL[k] : 0x7fffffff;
        int Rk = active ? posR[totLE - 1 - k] : -1;
        bool sw = active && (Lk < Rk);
        unsigned long long bm = __ballot(sw);     // monotone prefix of true
        int nsw = (~bm == 0ull) ? 64 : (__ffsll((long long)~bm) - 1);
        if (sw && (lane < nsw)) {
            unsigned long long tl = a[Lk], tr = a[Rk];
            a[Lk] = tr; a[Rk] = tl;              // all swapped positions distinct (proof R10)
        }
        K += nsw;
        if (nsw < 64) break;
    }
    wfence();
    int pi = posL[K];                             // K < totGE (pivot at pr-1 never swapped)
    if (K > 0) { int rp = posR[totLE - K]; if (rp < pi) pi = rp; }
    if (lane == 0) { tt = a[pi]; a[pi] = a[pr - 1]; a[pr - 1] = tt; }
    wfence();
    return pi;
}

__device__ __forceinline__ void lane_sift(unsigned long long* h, int start, int hm) {
    unsigned long long tmp = h[start];
    int i = start, j = start + start;
    while (j <= hm) {
        if (j < hm && keyval(h[j]) < keyval(h[j + 1])) ++j;
        if (keyval(tmp) < keyval(h[j])) { h[i] = h[j]; i = j; j += j; }
        else break;
    }
    h[i] = tmp;
}

// numpy aheapsort on a[lo..hi], extracting only positions >= needlo.
__device__ void wave_heap_top(unsigned long long* a, int lo, int hi, int needlo, int lane) {
    unsigned long long* h = a + lo - 1;
    int hm = hi - lo + 1;
    int half = hm >> 1;
    int maxlvl = 0; { int v = half; while (v >>= 1) ++maxlvl; }
    for (int lvl = maxlvl; lvl >= 0; --lvl) {
        int n0 = 1 << lvl;
        int n1 = (n0 << 1) - 1; if (n1 > half) n1 = half;
        for (int nb = n0; nb <= n1; nb += 64) {
            int node = nb + lane;
            if (node <= n1) lane_sift(h, node, hm);
        }
        wfence();
    }
    int E = hi - needlo + 1;
    if (E > hm - 1) E = hm - 1;
    if (lane == 0) {
        int m = hm;
        for (int e = 0; e < E; ++e) {
            unsigned long long tmp = h[m]; h[m] = h[1]; --m;
            int i = 1, j = 2;
            while (j <= m) {
                if (j < m && keyval(h[j]) < keyval(h[j + 1])) ++j;
                if (keyval(tmp) < keyval(h[j])) { h[i] = h[j]; i = j; j += j; }
                else break;
            }
            h[i] = tmp;
        }
    }
    wfence();
}

// stable insertion-sort outcome via parallel stable rank (len <= 16)
__device__ void wave_insertion(unsigned long long* a, int lo, int hi, int lane) {
    int len = hi - lo + 1;
    unsigned long long v = (lane < len) ? a[lo + lane] : 0ull;
    float fv = keyval(v);
    int rank = 0;
    for (int j = 0; j < len; ++j) {
        unsigned long long vj = __shfl(v, j, 64);
        float fj = keyval(vj);
        if ((fj < fv) || (fj == fv && j < lane)) ++rank;
    }
    wfence();
    if (lane < len) a[lo + rank] = v;
    wfence();
}

// numpy introsort (verified semantics: GLOBAL depth budget, SMALL=15,
// push-larger/continue-smaller), computing only positions >= n-NK exactly.
__device__ void wave_np_sort_top(unsigned long long* a, int n, int lane, int* stk,
                                 int* posL, int* posR) {
    int depth = 0; { int v = n; while (v >>= 1) ++depth; }
    depth *= 2;
    const int TOPLO = n - NK;
    int sp = 0;
    int lo = 0, hi = n - 1;
    for (;;) {
        while (hi - lo > 15) {
            if (depth-- < 0) {
                if (hi >= TOPLO) wave_heap_top(a, lo, hi, (lo > TOPLO ? lo : TOPLO), lane);
                goto pop;
            }
            {
                int pi = wave_partition_fast(a, posL, posR, lo, hi, lane);
                if (pi - lo < hi - pi) {
                    if (lane == 0) { stk[sp * 2] = pi + 1; stk[sp * 2 + 1] = hi; }
                    ++sp; hi = pi - 1;
                } else {
                    if (lane == 0) { stk[sp * 2] = lo; stk[sp * 2 + 1] = pi - 1; }
                    ++sp; lo = pi + 1;
                }
                wfence();
            }
        }
        if (hi > lo && hi >= TOPLO) wave_insertion(a, lo, hi, lane);
pop:
        if (sp == 0) break;
        --sp;
        lo = stk[sp * 2]; hi = stk[sp * 2 + 1];
    }
}

// Kernel 1: build packed tables ONCE per batch, fused with top1 extraction.
__global__ __launch_bounds__(256)
void build_tables_kernel(const int* __restrict__ hi, const float* __restrict__ hw,
                         float4* __restrict__ g_pack, uint16_t* __restrict__ g_lrc,
                         unsigned char* __restrict__ top1) {
    int j = blockIdx.x * 256 + threadIdx.x;
    if (j >= NB * LL * 16) return;
    int b = j >> 11;                 // LL*16 = 2048
    int lw = j & 2047;
    int l = lw >> 4, w = lw & 15, r = l + w;
    if (r >= LL) return;
    int sid = span_id(l, r);
    const int* hb = hi + b * LL * LL * 4;
    const float* wb = hw + b * LL * LL * 4;
    int4 iv = *(const int4*)(hb + (l * LL + r) * 4);
    float4 wv = *(const float4*)(wb + (l * LL + r) * 4);
    int ia = iv.x, ib = iv.y, ic = iv.z;
    float wa = wv.x, wb2 = wv.y, wc = wv.z;
    int m0, m1 = 255, m2 = 255;
    float W0, W1 = 0.f, W2 = 0.f;
    if (ia == ib && ib == ic) {
        m0 = ia; W0 = __fadd_rn(__fadd_rn(wa, wb2), wc);
    } else if (ia == ib) {
        float W = __fadd_rn(wa, wb2);
        if (ia < ic) { m0 = ia; W0 = W; m1 = ic; W1 = wc; }
        else         { m0 = ic; W0 = wc; m1 = ia; W1 = W; }
    } else if (ia == ic) {
        float W = __fadd_rn(wa, wc);
        if (ia < ib) { m0 = ia; W0 = W; m1 = ib; W1 = wb2; }
        else         { m0 = ib; W0 = wb2; m1 = ia; W1 = W; }
    } else if (ib == ic) {
        float W = __fadd_rn(wb2, wc);
        if (ia < ib) { m0 = ia; W0 = wa; m1 = ib; W1 = W; }
        else         { m0 = ib; W0 = W; m1 = ia; W1 = wa; }
    } else {
        int x0 = ia, x1 = ib, x2 = ic; float y0 = wa, y1 = wb2, y2 = wc;
        if (x0 > x1) { int tx = x0; x0 = x1; x1 = tx; float ty = y0; y0 = y1; y1 = ty; }
        if (x1 > x2) { int tx = x1; x1 = x2; x2 = tx; float ty = y1; y1 = y2; y2 = ty; }
        if (x0 > x1) { int tx = x0; x0 = x1; x1 = tx; float ty = y0; y0 = y1; y1 = ty; }
        m0 = x0; m1 = x1; m2 = x2; W0 = y0; W1 = y1; W2 = y2;
    }
    uint32_t rec = (uint32_t)m0 | ((uint32_t)m1 << 8) | ((uint32_t)m2 << 16)
                 | ((uint32_t)(ia & 127) << 24);
    g_pack[b * NS + sid] = make_float4(W0, W1, W2, __uint_as_float(rec));
    g_lrc[b * NS + sid] = (uint16_t)(l | (r << 7));
    top1[b * NS + sid] = (unsigned char)(ia & 127);
}

// Kernel 2: one wave per (b,l) — cumsum cap.
__global__ void cap_kernel(const unsigned char* __restrict__ top1,
                           unsigned char* __restrict__ flags) {
    int gw = (blockIdx.x * blockDim.x + threadIdx.x) >> 6;
    int lane = threadIdx.x & 63;
    int b = gw >> 7, l = gw & 127;
    const unsigned char* tb = top1 + b * NS;
    unsigned char* fb = flags + b * NS;
    int cnt = 0;
    for (int t0 = 0; t0 < NS; t0 += 64) {
        int t = t0 + lane;
        int tp = (t < NS) ? (int)tb[t] : 255;
        bool match = (tp == l);
        unsigned long long m = __ballot(match);
        if (match) {
            int pre = __popcll(m & ((1ull << lane) - 1ull));
            fb[t] = (cnt + pre + 1 <= 128) ? 1 : 0;
        }
        cnt += __popcll(m);
    }
}

// Cheap global->LDS table staging; cap bit folded into bit31 of rec
// (ri0 extracts use &63/&64 so bit31 never leaks).
__device__ __forceinline__ void load_tables(const float4* __restrict__ gp,
                                            const uint16_t* __restrict__ gl,
                                            const unsigned char* __restrict__ fb,
                                            float4* s_pack, uint16_t* s_lrc) {
    for (int j = threadIdx.x; j < NS; j += 256) {
        float4 v = gp[j];
        uint32_t rec = __float_as_uint(v.w) | ((uint32_t)(fb[j] & 1) << 31);
        v.w = __uint_as_float(rec);
        s_pack[j] = v;
        s_lrc[j] = gl[j];
    }
}

// Per-span prologue: q row (wave-wide, 128 entries, strided) + coverage ballots.
__device__ __forceinline__ void span_prologue(const float* __restrict__ db, float4 ps,
                                              int lane, float* qrow, int stride,
                                              unsigned long long* ub) {
    uint32_t rec = __float_as_uint(ps.w);
    int m0 = rec & 255, m1 = (rec >> 8) & 255, m2 = (rec >> 16) & 255;
    bool e1 = (m1 != 255), e2 = (m2 != 255);
    const float* row0 = db + m0 * LL;
    const float* row1 = db + (e1 ? m1 : 0) * LL;
    const float* row2 = db + (e2 ? m2 : 0) * LL;
    int mA = lane, mB = lane + 64;
    float dA0 = row0[mA], dB0 = row0[mB];
    float dA1 = row1[mA], dB1 = row1[mB];
    float dA2 = row2[mA], dB2 = row2[mB];
    float qA = __fmaf_rn(ps.x, npexp_f32(-dA0), 0.0f);
    qA = __fmaf_rn(ps.y, npexp_f32(-dA1), qA);
    qA = __fmaf_rn(ps.z, npexp_f32(-dA2), qA);
    float qB = __fmaf_rn(ps.x, npexp_f32(-dB0), 0.0f);
    qB = __fmaf_rn(ps.y, npexp_f32(-dB1), qB);
    qB = __fmaf_rn(ps.z, npexp_f32(-dB2), qB);
    bool cA = (dA0 <= 2.0f || mA == m0) ||
              (e1 && (dA1 <= 2.0f || mA == m1)) ||
              (e2 && (dA2 <= 2.0f || mA == m2));
    bool cB = (dB0 <= 2.0f || mB == m0) ||
              (e1 && (dB1 <= 2.0f || mB == m1)) ||
              (e2 && (dB2 <= 2.0f || mB == m2));
    ub[0] = __ballot(cA);
    ub[1] = __ballot(cB);
    qrow[mA * stride] = qA;
    qrow[mB * stride] = qB;
}

// Sorted top-11 merge step. Same semantics as the R10-verified version;
// LDS-free: uniform broadcasts via readlane; shfl_up(x,1) via DPP WAVE_SHR1
// (0x138: lane i reads lane i-1 — the prefix-scan direction; lane 0 invalid,
// bound_ctrl=false -> lane 0 receives 'old' = the 0xFFFFFFFF sentinel).
// R2 BUG: used 0x130 (WAVE_SHL1 = shfl_down) — wrong direction.
__device__ __forceinline__ void topk_merge(unsigned key, int t0, int lane,
                                           unsigned& v, int& vi, unsigned& tau) {
    unsigned long long bm = __ballot(key > tau);
    while (bm) {
        int ln = __ffsll((long long)bm) - 1;
        bm &= bm - 1;
        unsigned kk = (unsigned)__builtin_amdgcn_readlane((int)key, ln);
        if (kk > tau) {                    // wave-uniform
            int tk = t0 + ln;
            unsigned vprev = (unsigned)__builtin_amdgcn_update_dpp(
                -1, (int)v, 0x138 /*WAVE_SHR1*/, 0xF, 0xF, false);
            int iprev = __builtin_amdgcn_update_dpp(
                0, vi, 0x138 /*WAVE_SHR1*/, 0xF, 0xF, false);
            bool keep = (v >= kk);         // equals keep -> new after (asc-t among ties)
            bool fp = (vprev < kk);
            v = keep ? v : (fp ? vprev : kk);
            vi = keep ? vi : (fp ? iprev : tk);
            tau = (unsigned)__builtin_amdgcn_readlane((int)v, 10);
        }
    }
}

__device__ __forceinline__ void span_epilogue(unsigned v, int vi, int b, int s, int lane,
                                              unsigned char* __restrict__ rowflag,
                                              int* __restrict__ out) {
    unsigned vn = __shfl_down(v, 1, 64);
    bool tie = (lane < NK) && (v != 0u) && (vn == v);
    bool flag = (__ballot(tie) != 0ull);
    if (lane < NK) {
        int o = (b * NS + s) * NK + lane;
        out[NB * NS * NK + o] = 1;             // N_mask = ones always
        if (!flag) out[o] = (vi >= 0) ? vi : s;
    }
    if (lane == 0) rowflag[b * NS + s] = flag ? 1 : 0;
}

// Kernel A: fast path — 2 spans per wave, shared candidate decode,
// float2-packed q rows (one b64 gather serves both spans).
__global__ __launch_bounds__(256)
void span_scan_kernel(const float4* __restrict__ g_pack,
                      const uint16_t* __restrict__ g_lrc,
                      const float* __restrict__ dist,
                      const unsigned char* __restrict__ capf,
                      unsigned char* __restrict__ rowflag,
                      int* __restrict__ out) {
    __shared__ float4 s_pack[NS];
    __shared__ uint16_t s_lrc[NS];
    __shared__ float2 s_q2[WPB][LL];

    const int b = blockIdx.y;
    load_tables(g_pack + b * NS, g_lrc + b * NS, capf + b * NS, s_pack, s_lrc);
    __syncthreads();

    const int wid = threadIdx.x >> 6;
    const int lane = threadIdx.x & 63;
    const int base = blockIdx.x * (WPB * SPW);
    const int sA = base + wid;
    const int sB = base + WPB + wid;
    const int sAchunk = sA & ~63;
    const int sBchunk = sB & ~63;

    const float* db = dist + b * LL * LL;
    unsigned long long ubA0, ubA1, ubB0, ubB1;
    {
        unsigned long long ub[2];
        span_prologue(db, s_pack[sA], lane, &s_q2[wid][0].x, 2, ub);
        ubA0 = ub[0]; ubA1 = ub[1];
        span_prologue(db, s_pack[sB], lane, &s_q2[wid][0].y, 2, ub);
        ubB0 = ub[0]; ubB1 = ub[1];
    }
    uint32_t lrcA = s_lrc[sA], lrcB = s_lrc[sB];
    int lsA = lrcA & 127, rsA = (lrcA >> 7) & 127;
    int lsB = lrcB & 127, rsB = (lrcB >> 7) & 127;
    const float2* qq = s_q2[wid];

    unsigned vA = 0u, vB = 0u; int viA = -1, viB = -1; unsigned tauA = 0u, tauB = 0u;

    for (int t0 = 0; t0 < NS; t0 += 64) {
        int t = t0 + lane;
        unsigned keyA = 0u, keyB = 0u;
        if (t < NS) {
            float4 pt = s_pack[t];
            uint32_t rt = __float_as_uint(pt.w);
            int i0 = rt & 127, i1 = (rt >> 8) & 127, i2 = (rt >> 16) & 127;
            float2 q0 = qq[i0], q1 = qq[i1], q2 = qq[i2];
            uint32_t lr = s_lrc[t];
            int lt = lr & 127, rt2 = (lr >> 7) & 127;
            int rb = (int)(rt >> 24);
            bool cum = ((int)rt) < 0;      // cap bit (bit31)
            {   // span A
                float g = __fmaf_rn(pt.x, q0.x, 0.0f);
                g = __fmaf_rn(pt.y, q1.x, g);
                g = __fmaf_rn(pt.z, q2.x, g);
                int dl = lt - lsA; if (dl < 0) dl = -dl;
                int dr = rt2 - rsA; if (dr < 0) dr = -dr;
                bool geom = (dl <= 1) && (dr <= 1);
                unsigned long long bits = (rb & 64) ? ubA1 : ubA0;
                bool um = (((bits >> (rb & 63)) & 1ull) != 0) && cum;
                if (um || geom) keyA = __float_as_uint(g);   // gate >= 0 -> monotone u32
            }
            {   // span B
                float g = __fmaf_rn(pt.x, q0.y, 0.0f);
                g = __fmaf_rn(pt.y, q1.y, g);
                g = __fmaf_rn(pt.z, q2.y, g);
                int dl = lt - lsB; if (dl < 0) dl = -dl;
                int dr = rt2 - rsB; if (dr < 0) dr = -dr;
                bool geom = (dl <= 1) && (dr <= 1);
                unsigned long long bits = (rb & 64) ? ubB1 : ubB0;
                bool um = (((bits >> (rb & 63)) & 1ull) != 0) && cum;
                if (um || geom) keyB = __float_as_uint(g);
            }
            // self-exclusion (t != s), applied only in the span's own chunk
            if (t0 == sAchunk) keyA = (t == sA) ? 0u : keyA;
            if (t0 == sBchunk) keyB = (t == sB) ? 0u : keyB;
        }
        topk_merge(keyA, t0, lane, vA, viA, tauA);
        topk_merge(keyB, t0, lane, vB, viB, tauB);
    }

    span_epilogue(vA, viA, b, sA, lane, rowflag, out);
    span_epilogue(vB, viB, b, sB, lane, rowflag, out);
}

// Kernel B: slow path — exact numpy argsort(gate)[::-1][:K] for flagged rows.
// grid (NB, SLOTS); slot y handles flagged rows i with i % SLOTS == y.
__global__ __launch_bounds__(256)
void span_slow_kernel(const float4* __restrict__ g_pack,
                      const uint16_t* __restrict__ g_lrc,
                      const float* __restrict__ dist,
                      const unsigned char* __restrict__ capf,
                      const unsigned char* __restrict__ rowflag,
                      int* __restrict__ out) {
    __shared__ int s_nrows;
    __shared__ int s_rows[64];          // ceil(NS/SLOTS) = 61 max
    __shared__ float4 s_pack[NS];
    __shared__ uint16_t s_lrc[NS];
    __shared__ float s_qq[LL];
    __shared__ unsigned long long s_cov[2];
    __shared__ unsigned long long s_buf[NS];
    __shared__ int s_posL[NS], s_posR[NS];
    __shared__ int s_stk[48];

    const int b = blockIdx.x;
    const int slot = blockIdx.y;
    const unsigned char* rf = rowflag + b * NS;

    // wave 0 compacts this slot's flagged rows (ascending)
    if (threadIdx.x < 64) {
        int lane = threadIdx.x;
        int i = slot + lane * SLOTS;
        bool f = (i < NS) && (rf[i] != 0);
        unsigned long long m = __ballot(f);
        if (f) s_rows[__popcll(m & ((1ull << lane) - 1ull))] = i;
        if (lane == 0) s_nrows = __popcll(m);
    }
    __syncthreads();
    int nrows = s_nrows;
    if (nrows == 0) return;

    load_tables(g_pack + b * NS, g_lrc + b * NS, capf + b * NS, s_pack, s_lrc);
    __syncthreads();

    const int wid = threadIdx.x >> 6;
    const int lane = threadIdx.x & 63;
    const float* db = dist + b * LL * LL;

    for (int ri = 0; ri < nrows; ++ri) {
        const int s = s_rows[ri];
        uint32_t lrc = s_lrc[s];
        int ls = lrc & 127, rs = (lrc >> 7) & 127;

        if (wid == 0) {   // wave 0: q row + coverage ballots
            unsigned long long ub[2];
            span_prologue(db, s_pack[s], lane, s_qq, 1, ub);
            if (lane == 0) { s_cov[0] = ub[0]; s_cov[1] = ub[1]; }
        }
        __syncthreads();
        unsigned long long ub0 = s_cov[0], ub1 = s_cov[1];

        for (int t = threadIdx.x; t < NS; t += 256) {   // all threads: gate fill
            float4 pt = s_pack[t];
            uint32_t rt = __float_as_uint(pt.w);
            float g = __fmaf_rn(pt.x, s_qq[rt & 127], 0.0f);
            g = __fmaf_rn(pt.y, s_qq[(rt >> 8) & 127], g);
            g = __fmaf_rn(pt.z, s_qq[(rt >> 16) & 127], g);
            uint32_t lr = s_lrc[t];
            int lt = lr & 127, rt2 = (lr >> 7) & 127;
            int dl = lt - ls; if (dl < 0) dl = -dl;
            int dr = rt2 - rs; if (dr < 0) dr = -dr;
            bool neq = (t != s);
            bool geom = neq && (dl <= 1) && (dr <= 1);
            int rb = (int)(rt >> 24);
            unsigned long long bits = (rb & 64) ? ub1 : ub0;
            bool um = (((bits >> (rb & 63)) & 1ull) != 0) && (((int)rt) < 0) && neq;
            unsigned h32 = (um || geom) ? __float_as_uint(g) : 0xFF800000u;  // -inf
            s_buf[t] = ((unsigned long long)h32 << 32) | (unsigned)t;
        }
        __syncthreads();

        if (wid == 0) {
            wave_np_sort_top(s_buf, NS, lane, s_stk, s_posL, s_posR);
            if (lane < NK) {
                unsigned long long k = s_buf[NS - 1 - lane];  // reversed ascending
                int idx = ((unsigned)(k >> 32) == 0xFF800000u) ? s : (int)(k & 0xffffffffull);
                out[(b * NS + s) * NK + lane] = idx;
            }
        }
        __syncthreads();
    }
}

extern "C" void kernel_launch(void* const* d_in, const int* in_sizes, int n_in,
                              void* d_out, int out_size, void* d_ws, size_t ws_size,
                              hipStream_t stream) {
    const int* hi = (const int*)d_in[0];
    const float* hw = (const float*)d_in[1];
    const float* dist = (const float*)d_in[2];
    int* out = (int*)d_out;

    unsigned char* ws = (unsigned char*)d_ws;
    unsigned char* top1 = ws;                              // NB*NS
    unsigned char* capf = ws + NB * NS;                    // NB*NS
    unsigned char* rowflag = ws + 2 * NB * NS;             // NB*NS
    float4* g_pack = (float4*)(ws + 3 * NB * NS);          // NB*NS*16 (offset 46272, 16-aligned)
    uint16_t* g_lrc = (uint16_t*)(ws + 3 * NB * NS + NB * NS * 16);  // NB*NS*2

    build_tables_kernel<<<(NB * LL * 16) / 256, 256, 0, stream>>>(hi, hw, g_pack, g_lrc, top1);
    cap_kernel<<<(NB * LL * 64) / 256, 256, 0, stream>>>(top1, capf);
    dim3 grid(NS / (WPB * SPW), NB);
    span_scan_kernel<<<grid, 256, 0, stream>>>(g_pack, g_lrc, dist, capf, rowflag, out);
    dim3 sgrid(NB, SLOTS);
    span_slow_kernel<<<sgrid, 256, 0, stream>>>(g_pack, g_lrc, dist, capf, rowflag, out);
}

// Round 5
// 193.006 us; speedup vs baseline: 1.2410x; 1.0329x over previous
//
#include <hip/hip_runtime.h>
#include <stdint.h>

#define NB 8
#define LL 128
#define NS 1928      // number of spans (l,r), r-l+1 <= 16
#define NK 10        // top-k
#define WPB 4        // waves per block
#define SPW 4        // spans per wave (float4 q-pack)
#define SLOTS 32     // slow-path parallel slots per batch

// span id for (l, r): offset(l) + (r-l)
__device__ __forceinline__ int span_id(int l, int r) {
    int off = (l <= 112) ? (l << 4) : (NS - (((128 - l) * (129 - l)) >> 1));
    return off + (r - l);
}

// Replica of numpy's SIMD float32 exp (verified exact vs oracle in R9/R10).
__device__ __forceinline__ float npexp_f32(float x) {
    const float magic = 12582912.0f;
    const float log2e = 1.442695040888963f;
    const float c1 = -6.93145752e-1f;
    const float c2 = -1.42860677e-6f;
    float t = __fmul_rn(x, log2e);
    float q = __fsub_rn(__fadd_rn(t, magic), magic);
    float r = __fmaf_rn(q, c1, x);
    r = __fmaf_rn(q, c2, r);
    float num = __fmaf_rn(r, 5.082762527590693718096e-04f, 6.757896990527504603057e-03f);
    num = __fmaf_rn(num, r, 5.114512081637298353406e-02f);
    num = __fmaf_rn(num, r, 2.473615434895520810817e-01f);
    num = __fmaf_rn(num, r, 7.257664613233124478488e-01f);
    num = __fmaf_rn(num, r, 9.999999999980870924916e-01f);
    float den = __fmaf_rn(r, 2.159509375685829852307e-02f, -2.742335390411667452936e-01f);
    den = __fmaf_rn(den, r, 1.0f);
    float p = __fdiv_rn(num, den);
    int qi = (int)q;
    return __fmul_rn(p, __int_as_float((127 + qi) << 23));
}

__device__ __forceinline__ float keyval(unsigned long long k) {
    return __uint_as_float((unsigned)(k >> 32));
}

__device__ __forceinline__ float f4c(const float4& v, int x) {
    return x == 0 ? v.x : (x == 1 ? v.y : (x == 2 ? v.z : v.w));
}

__device__ __forceinline__ void wfence() {
    __builtin_amdgcn_wave_barrier();
    __threadfence_block();
    __builtin_amdgcn_wave_barrier();
}

// Wave-parallel numpy-aquicksort partition (R10-verified semantics), fast form.
__device__ int wave_partition_fast(unsigned long long* a, int* posL, int* posR,
                                   int pl, int pr, int lane) {
    int pm = pl + ((pr - pl) >> 1);
    unsigned long long vl = a[pl], vm = a[pm], vr = a[pr], tt;
    if (keyval(vm) < keyval(vl)) { tt = vm; vm = vl; vl = tt; }
    if (keyval(vr) < keyval(vm)) { tt = vr; vr = vm; vm = tt; }
    if (keyval(vm) < keyval(vl)) { tt = vm; vm = vl; vl = tt; }
    float vp = keyval(vm);
    unsigned long long vq = a[pr - 1];
    if (lane == 0) { a[pl] = vl; a[pr] = vr; a[pm] = vq; a[pr - 1] = vm; }
    wfence();

    unsigned long long lmask = (1ull << lane) - 1ull;
    int baseL = 0, baseR = 0;
    for (int p0 = pl; p0 <= pr; p0 += 64) {
        int pos = p0 + lane;
        bool inr = (pos <= pr);
        float v = inr ? keyval(a[pos]) : 0.0f;
        bool ge = inr && (pos > pl) && (pos < pr) && (v >= vp);
        bool le = inr && (pos <= pr - 2) && (v <= vp);
        unsigned long long bge = __ballot(ge);
        unsigned long long ble = __ballot(le);
        if (ge) posL[baseL + __popcll(bge & lmask)] = pos;
        if (le) posR[baseR + __popcll(ble & lmask)] = pos;
        baseL += __popcll(bge);
        baseR += __popcll(ble);
    }
    wfence();
    int totGE = baseL, totLE = baseR;
    int maxk = (totGE < totLE) ? totGE : totLE;
    int K = 0;
    for (int base = 0;; base += 64) {
        int k = base + lane;
        bool active = (k < maxk);
        int Lk = active ? posL[k] : 0x7fffffff;
        int Rk = active ? posR[totLE - 1 - k] : -1;
        bool sw = active && (Lk < Rk);
        unsigned long long bm = __ballot(sw);     // monotone prefix of true
        int nsw = (~bm == 0ull) ? 64 : (__ffsll((long long)~bm) - 1);
        if (sw && (lane < nsw)) {
            unsigned long long tl = a[Lk], tr = a[Rk];
            a[Lk] = tr; a[Rk] = tl;              // all swapped positions distinct (proof R10)
        }
        K += nsw;
        if (nsw < 64) break;
    }
    wfence();
    int pi = posL[K];                             // K < totGE (pivot at pr-1 never swapped)
    if (K > 0) { int rp = posR[totLE - K]; if (rp < pi) pi = rp; }
    if (lane == 0) { tt = a[pi]; a[pi] = a[pr - 1]; a[pr - 1] = tt; }
    wfence();
    return pi;
}

__device__ __forceinline__ void lane_sift(unsigned long long* h, int start, int hm) {
    unsigned long long tmp = h[start];
    int i = start, j = start + start;
    while (j <= hm) {
        if (j < hm && keyval(h[j]) < keyval(h[j + 1])) ++j;
        if (keyval(tmp) < keyval(h[j])) { h[i] = h[j]; i = j; j += j; }
        else break;
    }
    h[i] = tmp;
}

// numpy aheapsort on a[lo..hi], extracting only positions >= needlo.
__device__ void wave_heap_top(unsigned long long* a, int lo, int hi, int needlo, int lane) {
    unsigned long long* h = a + lo - 1;
    int hm = hi - lo + 1;
    int half = hm >> 1;
    int maxlvl = 0; { int v = half; while (v >>= 1) ++maxlvl; }
    for (int lvl = maxlvl; lvl >= 0; --lvl) {
        int n0 = 1 << lvl;
        int n1 = (n0 << 1) - 1; if (n1 > half) n1 = half;
        for (int nb = n0; nb <= n1; nb += 64) {
            int node = nb + lane;
            if (node <= n1) lane_sift(h, node, hm);
        }
        wfence();
    }
    int E = hi - needlo + 1;
    if (E > hm - 1) E = hm - 1;
    if (lane == 0) {
        int m = hm;
        for (int e = 0; e < E; ++e) {
            unsigned long long tmp = h[m]; h[m] = h[1]; --m;
            int i = 1, j = 2;
            while (j <= m) {
                if (j < m && keyval(h[j]) < keyval(h[j + 1])) ++j;
                if (keyval(tmp) < keyval(h[j])) { h[i] = h[j]; i = j; j += j; }
                else break;
            }
            h[i] = tmp;
        }
    }
    wfence();
}

// stable insertion-sort outcome via parallel stable rank (len <= 16)
__device__ void wave_insertion(unsigned long long* a, int lo, int hi, int lane) {
    int len = hi - lo + 1;
    unsigned long long v = (lane < len) ? a[lo + lane] : 0ull;
    float fv = keyval(v);
    int rank = 0;
    for (int j = 0; j < len; ++j) {
        unsigned long long vj = __shfl(v, j, 64);
        float fj = keyval(vj);
        if ((fj < fv) || (fj == fv && j < lane)) ++rank;
    }
    wfence();
    if (lane < len) a[lo + rank] = v;
    wfence();
}

// numpy introsort (verified semantics: GLOBAL depth budget, SMALL=15,
// push-larger/continue-smaller), computing only positions >= n-NK exactly.
__device__ void wave_np_sort_top(unsigned long long* a, int n, int lane, int* stk,
                                 int* posL, int* posR) {
    int depth = 0; { int v = n; while (v >>= 1) ++depth; }
    depth *= 2;
    const int TOPLO = n - NK;
    int sp = 0;
    int lo = 0, hi = n - 1;
    for (;;) {
        while (hi - lo > 15) {
            if (depth-- < 0) {
                if (hi >= TOPLO) wave_heap_top(a, lo, hi, (lo > TOPLO ? lo : TOPLO), lane);
                goto pop;
            }
            {
                int pi = wave_partition_fast(a, posL, posR, lo, hi, lane);
                if (pi - lo < hi - pi) {
                    if (lane == 0) { stk[sp * 2] = pi + 1; stk[sp * 2 + 1] = hi; }
                    ++sp; hi = pi - 1;
                } else {
                    if (lane == 0) { stk[sp * 2] = lo; stk[sp * 2 + 1] = pi - 1; }
                    ++sp; lo = pi + 1;
                }
                wfence();
            }
        }
        if (hi > lo && hi >= TOPLO) wave_insertion(a, lo, hi, lane);
pop:
        if (sp == 0) break;
        --sp;
        lo = stk[sp * 2]; hi = stk[sp * 2 + 1];
    }
}

// Kernel 1: build packed tables ONCE per batch, fused with top1 extraction.
__global__ __launch_bounds__(256)
void build_tables_kernel(const int* __restrict__ hi, const float* __restrict__ hw,
                         float4* __restrict__ g_pack, uint16_t* __restrict__ g_lrc,
                         unsigned char* __restrict__ top1) {
    int j = blockIdx.x * 256 + threadIdx.x;
    if (j >= NB * LL * 16) return;
    int b = j >> 11;                 // LL*16 = 2048
    int lw = j & 2047;
    int l = lw >> 4, w = lw & 15, r = l + w;
    if (r >= LL) return;
    int sid = span_id(l, r);
    const int* hb = hi + b * LL * LL * 4;
    const float* wb = hw + b * LL * LL * 4;
    int4 iv = *(const int4*)(hb + (l * LL + r) * 4);
    float4 wv = *(const float4*)(wb + (l * LL + r) * 4);
    int ia = iv.x, ib = iv.y, ic = iv.z;
    float wa = wv.x, wb2 = wv.y, wc = wv.z;
    int m0, m1 = 255, m2 = 255;
    float W0, W1 = 0.f, W2 = 0.f;
    if (ia == ib && ib == ic) {
        m0 = ia; W0 = __fadd_rn(__fadd_rn(wa, wb2), wc);
    } else if (ia == ib) {
        float W = __fadd_rn(wa, wb2);
        if (ia < ic) { m0 = ia; W0 = W; m1 = ic; W1 = wc; }
        else         { m0 = ic; W0 = wc; m1 = ia; W1 = W; }
    } else if (ia == ic) {
        float W = __fadd_rn(wa, wc);
        if (ia < ib) { m0 = ia; W0 = W; m1 = ib; W1 = wb2; }
        else         { m0 = ib; W0 = wb2; m1 = ia; W1 = W; }
    } else if (ib == ic) {
        float W = __fadd_rn(wb2, wc);
        if (ia < ib) { m0 = ia; W0 = wa; m1 = ib; W1 = W; }
        else         { m0 = ib; W0 = W; m1 = ia; W1 = wa; }
    } else {
        int x0 = ia, x1 = ib, x2 = ic; float y0 = wa, y1 = wb2, y2 = wc;
        if (x0 > x1) { int tx = x0; x0 = x1; x1 = tx; float ty = y0; y0 = y1; y1 = ty; }
        if (x1 > x2) { int tx = x1; x1 = x2; x2 = tx; float ty = y1; y1 = y2; y2 = ty; }
        if (x0 > x1) { int tx = x0; x0 = x1; x1 = tx; float ty = y0; y0 = y1; y1 = ty; }
        m0 = x0; m1 = x1; m2 = x2; W0 = y0; W1 = y1; W2 = y2;
    }
    uint32_t rec = (uint32_t)m0 | ((uint32_t)m1 << 8) | ((uint32_t)m2 << 16)
                 | ((uint32_t)(ia & 127) << 24);
    g_pack[b * NS + sid] = make_float4(W0, W1, W2, __uint_as_float(rec));
    g_lrc[b * NS + sid] = (uint16_t)(l | (r << 7));
    top1[b * NS + sid] = (unsigned char)(ia & 127);
}

// Kernel 2: one wave per (b,l) — cumsum cap.
__global__ void cap_kernel(const unsigned char* __restrict__ top1,
                           unsigned char* __restrict__ flags) {
    int gw = (blockIdx.x * blockDim.x + threadIdx.x) >> 6;
    int lane = threadIdx.x & 63;
    int b = gw >> 7, l = gw & 127;
    const unsigned char* tb = top1 + b * NS;
    unsigned char* fb = flags + b * NS;
    int cnt = 0;
    for (int t0 = 0; t0 < NS; t0 += 64) {
        int t = t0 + lane;
        int tp = (t < NS) ? (int)tb[t] : 255;
        bool match = (tp == l);
        unsigned long long m = __ballot(match);
        if (match) {
            int pre = __popcll(m & ((1ull << lane) - 1ull));
            fb[t] = (cnt + pre + 1 <= 128) ? 1 : 0;
        }
        cnt += __popcll(m);
    }
}

// Table staging for slow kernel (pack + lrc); cap bit folded into rec bit31.
__device__ __forceinline__ void load_tables(const float4* __restrict__ gp,
                                            const uint16_t* __restrict__ gl,
                                            const unsigned char* __restrict__ fb,
                                            float4* s_pack, uint16_t* s_lrc) {
    for (int j = threadIdx.x; j < NS; j += 256) {
        float4 v = gp[j];
        uint32_t rec = __float_as_uint(v.w) | ((uint32_t)(fb[j] & 1) << 31);
        v.w = __uint_as_float(rec);
        s_pack[j] = v;
        s_lrc[j] = gl[j];
    }
}

// Per-span prologue: q row (wave-wide, 128 entries, strided) + coverage ballots.
__device__ __forceinline__ void span_prologue(const float* __restrict__ db, float4 ps,
                                              int lane, float* qrow, int stride,
                                              unsigned long long* ub) {
    uint32_t rec = __float_as_uint(ps.w);
    int m0 = rec & 255, m1 = (rec >> 8) & 255, m2 = (rec >> 16) & 255;
    bool e1 = (m1 != 255), e2 = (m2 != 255);
    const float* row0 = db + m0 * LL;
    const float* row1 = db + (e1 ? m1 : 0) * LL;
    const float* row2 = db + (e2 ? m2 : 0) * LL;
    int mA = lane, mB = lane + 64;
    float dA0 = row0[mA], dB0 = row0[mB];
    float dA1 = row1[mA], dB1 = row1[mB];
    float dA2 = row2[mA], dB2 = row2[mB];
    float qA = __fmaf_rn(ps.x, npexp_f32(-dA0), 0.0f);
    qA = __fmaf_rn(ps.y, npexp_f32(-dA1), qA);
    qA = __fmaf_rn(ps.z, npexp_f32(-dA2), qA);
    float qB = __fmaf_rn(ps.x, npexp_f32(-dB0), 0.0f);
    qB = __fmaf_rn(ps.y, npexp_f32(-dB1), qB);
    qB = __fmaf_rn(ps.z, npexp_f32(-dB2), qB);
    bool cA = (dA0 <= 2.0f || mA == m0) ||
              (e1 && (dA1 <= 2.0f || mA == m1)) ||
              (e2 && (dA2 <= 2.0f || mA == m2));
    bool cB = (dB0 <= 2.0f || mB == m0) ||
              (e1 && (dB1 <= 2.0f || mB == m1)) ||
              (e2 && (dB2 <= 2.0f || mB == m2));
    ub[0] = __ballot(cA);
    ub[1] = __ballot(cB);
    qrow[mA * stride] = qA;
    qrow[mB * stride] = qB;
}

// Sorted top-11 merge step (R10-verified semantics). LDS-free: readlane
// broadcasts + DPP WAVE_SHR1 (lane i reads lane i-1; lane 0 gets 'old').
__device__ __forceinline__ void topk_merge(unsigned key, int t0, int lane,
                                           unsigned& v, int& vi, unsigned& tau) {
    unsigned long long bm = __ballot(key > tau);
    while (bm) {
        int ln = __ffsll((long long)bm) - 1;
        bm &= bm - 1;
        unsigned kk = (unsigned)__builtin_amdgcn_readlane((int)key, ln);
        if (kk > tau) {                    // wave-uniform
            int tk = t0 + ln;
            unsigned vprev = (unsigned)__builtin_amdgcn_update_dpp(
                -1, (int)v, 0x138 /*WAVE_SHR1*/, 0xF, 0xF, false);
            int iprev = __builtin_amdgcn_update_dpp(
                0, vi, 0x138 /*WAVE_SHR1*/, 0xF, 0xF, false);
            bool keep = (v >= kk);         // equals keep -> new after (asc-t among ties)
            bool fp = (vprev < kk);
            v = keep ? v : (fp ? vprev : kk);
            vi = keep ? vi : (fp ? iprev : tk);
            tau = (unsigned)__builtin_amdgcn_readlane((int)v, 10);
        }
    }
}

// Variant with per-lane candidate index (for the geom post-pass).
__device__ __forceinline__ void topk_merge_idx(unsigned key, int tval,
                                               unsigned& v, int& vi, unsigned& tau) {
    unsigned long long bm = __ballot(key > tau);
    while (bm) {
        int ln = __ffsll((long long)bm) - 1;
        bm &= bm - 1;
        unsigned kk = (unsigned)__builtin_amdgcn_readlane((int)key, ln);
        if (kk > tau) {
            int tk = __builtin_amdgcn_readlane(tval, ln);
            unsigned vprev = (unsigned)__builtin_amdgcn_update_dpp(
                -1, (int)v, 0x138, 0xF, 0xF, false);
            int iprev = __builtin_amdgcn_update_dpp(
                0, vi, 0x138, 0xF, 0xF, false);
            bool keep = (v >= kk);
            bool fp = (vprev < kk);
            v = keep ? v : (fp ? vprev : kk);
            vi = keep ? vi : (fp ? iprev : tk);
            tau = (unsigned)__builtin_amdgcn_readlane((int)v, 10);
        }
    }
}

__device__ __forceinline__ void span_epilogue(unsigned v, int vi, int b, int s, int lane,
                                              unsigned char* __restrict__ rowflag,
                                              int* __restrict__ out) {
    unsigned vn = __shfl_down(v, 1, 64);
    bool tie = (lane < NK) && (v != 0u) && (vn == v);
    bool flag = (__ballot(tie) != 0ull);
    if (lane < NK) {
        int o = (b * NS + s) * NK + lane;
        out[NB * NS * NK + o] = 1;             // N_mask = ones always
        if (!flag) out[o] = (vi >= 0) ? vi : s;
    }
    if (lane == 0) rowflag[b * NS + s] = flag ? 1 : 0;
}

// Kernel A: fast path — 4 spans per wave; main loop keys on um only
// (geometry handled by a <=8-candidate post-pass via span_id of neighbors).
__global__ __launch_bounds__(256)
void span_scan_kernel(const float4* __restrict__ g_pack,
                      const uint16_t* __restrict__ g_lrc,
                      const float* __restrict__ dist,
                      const unsigned char* __restrict__ capf,
                      unsigned char* __restrict__ rowflag,
                      int* __restrict__ out) {
    __shared__ float4 s_pack[NS];
    __shared__ float4 s_q4[WPB][LL];

    const int b = blockIdx.y;
    {
        const float4* gp = g_pack + b * NS;
        const unsigned char* fb = capf + b * NS;
        for (int j = threadIdx.x; j < NS; j += 256) {
            float4 v = gp[j];
            v.w = __uint_as_float(__float_as_uint(v.w) | ((uint32_t)(fb[j] & 1) << 31));
            s_pack[j] = v;
        }
    }
    __syncthreads();

    const int wid = threadIdx.x >> 6;
    const int lane = threadIdx.x & 63;
    const int base = blockIdx.x * (WPB * SPW);
    const float* db = dist + b * LL * LL;
    const uint16_t* glb = g_lrc + b * NS;

    int ss[SPW]; bool ok[SPW]; int schunk[SPW];
    int lsv[SPW], rsv[SPW];
    unsigned long long ub0[SPW], ub1[SPW];

    #pragma unroll
    for (int x = 0; x < SPW; ++x) {
        int s = base + x * WPB + wid;
        ok[x] = (s < NS);
        s = ok[x] ? s : 0;
        ss[x] = s;
        schunk[x] = s & ~63;
        uint32_t lrc = glb[s];
        lsv[x] = lrc & 127;
        rsv[x] = (lrc >> 7) & 127;
        unsigned long long ub[2];
        span_prologue(db, s_pack[s], lane, (float*)&s_q4[wid][0] + x, 4, ub);
        ub0[x] = ub[0]; ub1[x] = ub[1];
    }
    const float4* qq = s_q4[wid];

    unsigned v[SPW] = {0u, 0u, 0u, 0u};
    int vi[SPW] = {-1, -1, -1, -1};
    unsigned tau[SPW] = {0u, 0u, 0u, 0u};

    for (int t0 = 0; t0 < NS; t0 += 64) {
        int t = t0 + lane;
        unsigned key[SPW] = {0u, 0u, 0u, 0u};
        if (t < NS) {
            float4 pt = s_pack[t];
            uint32_t rt = __float_as_uint(pt.w);
            float4 q0 = qq[rt & 127];
            float4 q1 = qq[(rt >> 8) & 127];
            float4 q2 = qq[(rt >> 16) & 127];
            int sh = (int)((rt >> 24) & 63);
            bool hi2 = ((rt >> 24) & 64) != 0;
            bool cum = ((int)rt) < 0;      // cap bit (bit31)
            #pragma unroll
            for (int x = 0; x < SPW; ++x) {
                float g = __fmaf_rn(pt.x, f4c(q0, x), 0.0f);
                g = __fmaf_rn(pt.y, f4c(q1, x), g);
                g = __fmaf_rn(pt.z, f4c(q2, x), g);
                unsigned long long bits = hi2 ? ub1[x] : ub0[x];
                bool um = (((bits >> sh) & 1ull) != 0) && cum;
                key[x] = um ? __float_as_uint(g) : 0u;   // gate >= 0 -> monotone u32
            }
            #pragma unroll
            for (int x = 0; x < SPW; ++x)
                if (t0 == schunk[x]) key[x] = (t == ss[x]) ? 0u : key[x];
        }
        #pragma unroll
        for (int x = 0; x < SPW; ++x)
            topk_merge(key[x], t0, lane, v[x], vi[x], tau[x]);
    }

    // geom post-pass: <=8 lattice neighbors per span, merged if not already
    // included via um. Lanes 0..7 enumerate neighbors in ascending-t order.
    {
        int j = lane + (lane >= 4 ? 1 : 0);           // skip (0,0)
        int dl = j / 3 - 1, dr = j % 3 - 1;
        #pragma unroll
        for (int x = 0; x < SPW; ++x) {
            int nl = lsv[x] + dl, nr = rsv[x] + dr;
            bool valid = (lane < 8) && (nl >= 0) && (nr >= nl) && (nr < LL)
                         && (nr - nl < 16);
            int tg = valid ? span_id(nl, nr) : 0;
            float4 pt = s_pack[tg];
            uint32_t rt = __float_as_uint(pt.w);
            float g = __fmaf_rn(pt.x, f4c(qq[rt & 127], x), 0.0f);
            g = __fmaf_rn(pt.y, f4c(qq[(rt >> 8) & 127], x), g);
            g = __fmaf_rn(pt.z, f4c(qq[(rt >> 16) & 127], x), g);
            int rb = (int)(rt >> 24);
            unsigned long long bits = (rb & 64) ? ub1[x] : ub0[x];
            bool um = (((bits >> (rb & 63)) & 1ull) != 0) && (((int)rt) < 0);
            unsigned key = (valid && !um) ? __float_as_uint(g) : 0u;
            topk_merge_idx(key, tg, v[x], vi[x], tau[x]);
        }
    }

    #pragma unroll
    for (int x = 0; x < SPW; ++x)
        if (ok[x]) span_epilogue(v[x], vi[x], b, ss[x], lane, rowflag, out);
}

// Kernel B: slow path — exact numpy argsort(gate)[::-1][:K] for flagged rows.
// grid (NB, SLOTS); slot y handles flagged rows i with i % SLOTS == y.
__global__ __launch_bounds__(256)
void span_slow_kernel(const float4* __restrict__ g_pack,
                      const uint16_t* __restrict__ g_lrc,
                      const float* __restrict__ dist,
                      const unsigned char* __restrict__ capf,
                      const unsigned char* __restrict__ rowflag,
                      int* __restrict__ out) {
    __shared__ int s_nrows;
    __shared__ int s_rows[64];          // ceil(NS/SLOTS) = 61 max
    __shared__ float4 s_pack[NS];
    __shared__ uint16_t s_lrc[NS];
    __shared__ float s_qq[LL];
    __shared__ unsigned long long s_cov[2];
    __shared__ unsigned long long s_buf[NS];
    __shared__ int s_posL[NS], s_posR[NS];
    __shared__ int s_stk[48];

    const int b = blockIdx.x;
    const int slot = blockIdx.y;
    const unsigned char* rf = rowflag + b * NS;

    // wave 0 compacts this slot's flagged rows (ascending)
    if (threadIdx.x < 64) {
        int lane = threadIdx.x;
        int i = slot + lane * SLOTS;
        bool f = (i < NS) && (rf[i] != 0);
        unsigned long long m = __ballot(f);
        if (f) s_rows[__popcll(m & ((1ull << lane) - 1ull))] = i;
        if (lane == 0) s_nrows = __popcll(m);
    }
    __syncthreads();
    int nrows = s_nrows;
    if (nrows == 0) return;

    load_tables(g_pack + b * NS, g_lrc + b * NS, capf + b * NS, s_pack, s_lrc);
    __syncthreads();

    const int wid = threadIdx.x >> 6;
    const int lane = threadIdx.x & 63;
    const float* db = dist + b * LL * LL;

    for (int ri = 0; ri < nrows; ++ri) {
        const int s = s_rows[ri];
        uint32_t lrc = s_lrc[s];
        int ls = lrc & 127, rs = (lrc >> 7) & 127;

        if (wid == 0) {   // wave 0: q row + coverage ballots
            unsigned long long ub[2];
            span_prologue(db, s_pack[s], lane, s_qq, 1, ub);
            if (lane == 0) { s_cov[0] = ub[0]; s_cov[1] = ub[1]; }
        }
        __syncthreads();
        unsigned long long ub0 = s_cov[0], ub1 = s_cov[1];

        for (int t = threadIdx.x; t < NS; t += 256) {   // all threads: gate fill
            float4 pt = s_pack[t];
            uint32_t rt = __float_as_uint(pt.w);
            float g = __fmaf_rn(pt.x, s_qq[rt & 127], 0.0f);
            g = __fmaf_rn(pt.y, s_qq[(rt >> 8) & 127], g);
            g = __fmaf_rn(pt.z, s_qq[(rt >> 16) & 127], g);
            uint32_t lr = s_lrc[t];
            int lt = lr & 127, rt2 = (lr >> 7) & 127;
            int dl = lt - ls; if (dl < 0) dl = -dl;
            int dr = rt2 - rs; if (dr < 0) dr = -dr;
            bool neq = (t != s);
            bool geom = neq && (dl <= 1) && (dr <= 1);
            int rb = (int)(rt >> 24);
            unsigned long long bits = (rb & 64) ? ub1 : ub0;
            bool um = (((bits >> (rb & 63)) & 1ull) != 0) && (((int)rt) < 0) && neq;
            unsigned h32 = (um || geom) ? __float_as_uint(g) : 0xFF800000u;  // -inf
            s_buf[t] = ((unsigned long long)h32 << 32) | (unsigned)t;
        }
        __syncthreads();

        if (wid == 0) {
            wave_np_sort_top(s_buf, NS, lane, s_stk, s_posL, s_posR);
            if (lane < NK) {
                unsigned long long k = s_buf[NS - 1 - lane];  // reversed ascending
                int idx = ((unsigned)(k >> 32) == 0xFF800000u) ? s : (int)(k & 0xffffffffull);
                out[(b * NS + s) * NK + lane] = idx;
            }
        }
        __syncthreads();
    }
}

extern "C" void kernel_launch(void* const* d_in, const int* in_sizes, int n_in,
                              void* d_out, int out_size, void* d_ws, size_t ws_size,
                              hipStream_t stream) {
    const int* hi = (const int*)d_in[0];
    const float* hw = (const float*)d_in[1];
    const float* dist = (const float*)d_in[2];
    int* out = (int*)d_out;

    unsigned char* ws = (unsigned char*)d_ws;
    unsigned char* top1 = ws;                              // NB*NS
    unsigned char* capf = ws + NB * NS;                    // NB*NS
    unsigned char* rowflag = ws + 2 * NB * NS;             // NB*NS
    float4* g_pack = (float4*)(ws + 3 * NB * NS);          // NB*NS*16 (offset 46272, 16-aligned)
    uint16_t* g_lrc = (uint16_t*)(ws + 3 * NB * NS + NB * NS * 16);  // NB*NS*2

    build_tables_kernel<<<(NB * LL * 16) / 256, 256, 0, stream>>>(hi, hw, g_pack, g_lrc, top1);
    cap_kernel<<<(NB * LL * 64) / 256, 256, 0, stream>>>(top1, capf);
    dim3 grid((NS + WPB * SPW - 1) / (WPB * SPW), NB);
    span_scan_kernel<<<grid, 256, 0, stream>>>(g_pack, g_lrc, dist, capf, rowflag, out);
    dim3 sgrid(NB, SLOTS);
    span_slow_kernel<<<sgrid, 256, 0, stream>>>(g_pack, g_lrc, dist, capf, rowflag, out);
}